// Round 20
// baseline (243.007 us; speedup 1.0000x reference)
//
#include <hip/hip_runtime.h>

typedef unsigned short u16;
typedef _Float16 h8v __attribute__((ext_vector_type(8)));
typedef __attribute__((ext_vector_type(4))) float f4v;

#define DEV static __device__ __forceinline__

// f32 -> fp16 bits (RNE via hardware cvt)
DEV u16 f2h(float f) {
  union { _Float16 h; u16 u; } v; v.h = (_Float16)f; return v.u;
}
DEV float h2f(u16 u) {
  union { u16 u; _Float16 h; } v; v.u = u; return (float)v.h;
}

DEV f4v mfma16h(h8v a, h8v b, f4v c) {
  return __builtin_amdgcn_mfma_f32_16x16x32_f16(a, b, c, 0, 0, 0);
}

// segment lookup for transpose tile index t in [0, 7168)
DEV void segT(int t,
    const float* wq, const float* wk, const float* wv, const float* wo,
    const float* shg, const float* shu, const float* shd,
    const float* wg, const float* wu, const float* wd,
    u16* wqkvT, u16* woT, u16* shguT, u16* shdT, u16* wguT, u16* wdT,
    const float*& in, u16*& out, int& R, int& C, int& gx, int& gy,
    long long& ozs, int& rmul, int& radd, int& base) {
  if (t < 256)       { in=wq;  out=wqkvT;                    R=1024; C=1024; gx=16; gy=16; ozs=0;        base=0;    rmul=1; radd=0; }
  else if (t < 320)  { in=wk;  out=wqkvT+(size_t)1024*1024;  R=1024; C=256;  gx=4;  gy=16; ozs=0;        base=256;  rmul=1; radd=0; }
  else if (t < 384)  { in=wv;  out=wqkvT+(size_t)1280*1024;  R=1024; C=256;  gx=4;  gy=16; ozs=0;        base=320;  rmul=1; radd=0; }
  else if (t < 640)  { in=wo;  out=woT;                      R=1024; C=1024; gx=16; gy=16; ozs=0;        base=384;  rmul=1; radd=0; }
  else if (t < 768)  { in=shg; out=shguT;                    R=1024; C=512;  gx=8;  gy=16; ozs=0;        base=640;  rmul=2; radd=0; }
  else if (t < 896)  { in=shu; out=shguT;                    R=1024; C=512;  gx=8;  gy=16; ozs=0;        base=768;  rmul=2; radd=1; }
  else if (t < 1024) { in=shd; out=shdT;                     R=512;  C=1024; gx=16; gy=8;  ozs=0;        base=896;  rmul=1; radd=0; }
  else if (t < 3072) { in=wg;  out=wguT;                     R=1024; C=256;  gx=4;  gy=16; ozs=512*1024; base=1024; rmul=2; radd=0; }
  else if (t < 5120) { in=wu;  out=wguT;                     R=1024; C=256;  gx=4;  gy=16; ozs=512*1024; base=3072; rmul=2; radd=1; }
  else               { in=wd;  out=wdT;                      R=256;  C=1024; gx=16; gy=4;  ozs=256*1024; base=5120; rmul=1; radd=0; }
}

// ---------------- prep: ALL weight transposes + rmsnorm1 + zero_counts ----------------
// R20: 2 tiles/block with T14 register prefetch — tile t+1's reads are issued
// BEFORE the write phase of tile t (named float4 regs, no arrays). Same
// values, same rounding, reordered in time. Discriminates latency-bound vs
// L3-BW-bound for prep: replay counters show reads served from L3 (weights
// stay Infinity-Cache-resident across graph replays), writes to HBM.
__global__ __launch_bounds__(256) void prep_kernel(
    const float* __restrict__ wq, const float* __restrict__ wk,
    const float* __restrict__ wv, const float* __restrict__ wo,
    const float* __restrict__ shg, const float* __restrict__ shu,
    const float* __restrict__ shd,
    const float* __restrict__ wg, const float* __restrict__ wu,
    const float* __restrict__ wd,
    u16* __restrict__ wqkvT, u16* __restrict__ woT, u16* __restrict__ shguT,
    u16* __restrict__ shdT, u16* __restrict__ wguT, u16* __restrict__ wdT,
    const float* __restrict__ x, const float* __restrict__ n1w,
    u16* __restrict__ hH, int* __restrict__ counts) {
  int blk = blockIdx.x;
  if (blk < 3584) {
    __shared__ float tile[64][65];
    int tcol = (threadIdx.x & 15) * 4;
    int trow = threadIdx.x >> 4;         // 0..15
    int tcol8 = (threadIdx.x & 7) * 8;
    int trow2 = threadIdx.x >> 3;        // 0..31

    int t0 = blk*2, t1 = t0 + 1;
    // ---- tile t0: lookup + read + LDS store ----
    const float* in0; u16* out0; int R0,C0,gx0,gy0,rmul0,radd0,base0; long long ozs0;
    segT(t0, wq,wk,wv,wo,shg,shu,shd,wg,wu,wd, wqkvT,woT,shguT,shdT,wguT,wdT,
         in0,out0,R0,C0,gx0,gy0,ozs0,rmul0,radd0,base0);
    int i0 = t0 - base0;
    int bx0 = i0 % gx0; int rem0 = i0 / gx0; int by0 = rem0 % gy0; int z0 = rem0 / gy0;
    const float* inp0 = in0 + (size_t)z0 * R0 * C0;
    u16* op0 = out0 + (size_t)z0 * ozs0;
    int c00 = bx0 * 64, r00 = by0 * 64;
    float4 v0 = *(const float4*)(inp0 + (size_t)(r00+trow   )*C0 + c00 + tcol);
    float4 v1 = *(const float4*)(inp0 + (size_t)(r00+trow+16)*C0 + c00 + tcol);
    float4 v2 = *(const float4*)(inp0 + (size_t)(r00+trow+32)*C0 + c00 + tcol);
    float4 v3 = *(const float4*)(inp0 + (size_t)(r00+trow+48)*C0 + c00 + tcol);
    tile[trow   ][tcol]=v0.x; tile[trow   ][tcol+1]=v0.y; tile[trow   ][tcol+2]=v0.z; tile[trow   ][tcol+3]=v0.w;
    tile[trow+16][tcol]=v1.x; tile[trow+16][tcol+1]=v1.y; tile[trow+16][tcol+2]=v1.z; tile[trow+16][tcol+3]=v1.w;
    tile[trow+32][tcol]=v2.x; tile[trow+32][tcol+1]=v2.y; tile[trow+32][tcol+2]=v2.z; tile[trow+32][tcol+3]=v2.w;
    tile[trow+48][tcol]=v3.x; tile[trow+48][tcol+1]=v3.y; tile[trow+48][tcol+2]=v3.z; tile[trow+48][tcol+3]=v3.w;

    // ---- prefetch tile t1 into registers (hidden under t0's write phase) ----
    const float* in1; u16* out1; int R1,C1,gx1,gy1,rmul1,radd1,base1; long long ozs1;
    segT(t1, wq,wk,wv,wo,shg,shu,shd,wg,wu,wd, wqkvT,woT,shguT,shdT,wguT,wdT,
         in1,out1,R1,C1,gx1,gy1,ozs1,rmul1,radd1,base1);
    int i1 = t1 - base1;
    int bx1 = i1 % gx1; int rem1 = i1 / gx1; int by1 = rem1 % gy1; int z1 = rem1 / gy1;
    const float* inp1 = in1 + (size_t)z1 * R1 * C1;
    u16* op1 = out1 + (size_t)z1 * ozs1;
    int c01 = bx1 * 64, r01 = by1 * 64;
    float4 w0 = *(const float4*)(inp1 + (size_t)(r01+trow   )*C1 + c01 + tcol);
    float4 w1 = *(const float4*)(inp1 + (size_t)(r01+trow+16)*C1 + c01 + tcol);
    float4 w2 = *(const float4*)(inp1 + (size_t)(r01+trow+32)*C1 + c01 + tcol);
    float4 w3 = *(const float4*)(inp1 + (size_t)(r01+trow+48)*C1 + c01 + tcol);

    #define WPHASE(op_, R_, rmul_, radd_, c0_, r0_) { \
      int c = trow2; \
      uint4 ov; \
      ov.x = (unsigned)f2h(tile[tcol8+0][c]) | ((unsigned)f2h(tile[tcol8+1][c]) << 16); \
      ov.y = (unsigned)f2h(tile[tcol8+2][c]) | ((unsigned)f2h(tile[tcol8+3][c]) << 16); \
      ov.z = (unsigned)f2h(tile[tcol8+4][c]) | ((unsigned)f2h(tile[tcol8+5][c]) << 16); \
      ov.w = (unsigned)f2h(tile[tcol8+6][c]) | ((unsigned)f2h(tile[tcol8+7][c]) << 16); \
      *(uint4*)(op_ + (size_t)(((c0_)+c)*(rmul_) + (radd_))*(R_) + (r0_) + tcol8) = ov; \
      c = trow2 + 32; \
      ov.x = (unsigned)f2h(tile[tcol8+0][c]) | ((unsigned)f2h(tile[tcol8+1][c]) << 16); \
      ov.y = (unsigned)f2h(tile[tcol8+2][c]) | ((unsigned)f2h(tile[tcol8+3][c]) << 16); \
      ov.z = (unsigned)f2h(tile[tcol8+4][c]) | ((unsigned)f2h(tile[tcol8+5][c]) << 16); \
      ov.w = (unsigned)f2h(tile[tcol8+6][c]) | ((unsigned)f2h(tile[tcol8+7][c]) << 16); \
      *(uint4*)(op_ + (size_t)(((c0_)+c)*(rmul_) + (radd_))*(R_) + (r0_) + tcol8) = ov; \
    }

    __syncthreads();                 // t0 tile staged
    WPHASE(op0, R0, rmul0, radd0, c00, r00);
    __syncthreads();                 // all done reading t0's LDS
    tile[trow   ][tcol]=w0.x; tile[trow   ][tcol+1]=w0.y; tile[trow   ][tcol+2]=w0.z; tile[trow   ][tcol+3]=w0.w;
    tile[trow+16][tcol]=w1.x; tile[trow+16][tcol+1]=w1.y; tile[trow+16][tcol+2]=w1.z; tile[trow+16][tcol+3]=w1.w;
    tile[trow+32][tcol]=w2.x; tile[trow+32][tcol+1]=w2.y; tile[trow+32][tcol+2]=w2.z; tile[trow+32][tcol+3]=w2.w;
    tile[trow+48][tcol]=w3.x; tile[trow+48][tcol+1]=w3.y; tile[trow+48][tcol+2]=w3.z; tile[trow+48][tcol+3]=w3.w;
    __syncthreads();                 // t1 tile staged
    WPHASE(op1, R1, rmul1, radd1, c01, r01);
    #undef WPHASE
  } else if (blk < 5632) {
    // ---- rmsnorm1: x row -> fp16 hH row
    int n = blk - 3584;
    int t = threadIdx.x;
    const float* xr = x + (size_t)n * 1024;
    float4 v = ((const float4*)xr)[t];
    float ss = v.x*v.x + v.y*v.y + v.z*v.z + v.w*v.w;
    #pragma unroll
    for (int o = 1; o < 64; o <<= 1) ss += __shfl_xor(ss, o, 64);
    __shared__ float wsum[4];
    if ((t & 63) == 0) wsum[t >> 6] = ss;
    __syncthreads();
    float tot = wsum[0] + wsum[1] + wsum[2] + wsum[3];
    float rs = rsqrtf(tot * (1.0f/1024.0f) + 1e-6f);
    float4 wv4 = ((const float4*)n1w)[t];
    ushort4 oh = { f2h(v.x*rs*wv4.x), f2h(v.y*rs*wv4.y),
                   f2h(v.z*rs*wv4.z), f2h(v.w*rs*wv4.w) };
    ((ushort4*)(hH + (size_t)n*1024))[t] = oh;
  } else {
    if (threadIdx.x < 32) counts[threadIdx.x] = 0;
  }
}

// ---------------- rmsnorm (f32 in -> fp16 out [+ optional f32 out]) ----------------
__global__ __launch_bounds__(256) void rmsnorm_kernel(const float* __restrict__ xin,
                                                      const float* __restrict__ w,
                                                      u16* __restrict__ outH,
                                                      float* __restrict__ outF) {
  int n = blockIdx.x;
  int t = threadIdx.x;
  const float* xr = xin + (size_t)n * 1024;
  float4 v = ((const float4*)xr)[t];
  float ss = v.x*v.x + v.y*v.y + v.z*v.z + v.w*v.w;
  #pragma unroll
  for (int o = 1; o < 64; o <<= 1) ss += __shfl_xor(ss, o, 64);
  __shared__ float wsum[4];
  if ((t & 63) == 0) wsum[t >> 6] = ss;
  __syncthreads();
  float tot = wsum[0] + wsum[1] + wsum[2] + wsum[3];
  float rs = rsqrtf(tot * (1.0f/1024.0f) + 1e-6f);
  float4 wv = ((const float4*)w)[t];
  float o0 = v.x*rs*wv.x, o1 = v.y*rs*wv.y, o2 = v.z*rs*wv.z, o3 = v.w*rs*wv.w;
  if (outF) {
    float4 of = {o0, o1, o2, o3};
    ((float4*)(outF + (size_t)n*1024))[t] = of;
  }
  ushort4 oh = { f2h(o0), f2h(o1), f2h(o2), f2h(o3) };
  ((ushort4*)(outH + (size_t)n*1024))[t] = oh;
}

// ---------------- GEMM BM=64 BN=64 BK=64 (proven config, fp16): C = A x BT^T ----------------
// Tile growth (BM/BN/BK) loses to block count in this 2-barrier structure
// (3x confirmed). Epilogue variants: C f32(+resid) | Ch16 fp16 | Csilu fused
// silu(g)*u from interleaved (g,u) cols via shfl_xor(1), even lanes write.
__global__ __launch_bounds__(256) void gemm_kernel(
    const u16* __restrict__ Ah,
    const u16* __restrict__ Bh,
    float* __restrict__ C, u16* __restrict__ Ch16,
    u16* __restrict__ Csilu, const float* __restrict__ wtpP,
    const float* __restrict__ resid,
    const int* __restrict__ rowIdx, const int* __restrict__ counts,
    const int* __restrict__ offsets,
    int M, int N, int K, int strideBTe) {
  int M_ = M;
  const int* rIdx = rowIdx;
  int aOff = 0;
  if (counts) {
    int e = blockIdx.z;
    M_ = counts[e];
    if ((int)blockIdx.y * 64 >= M_) return;
    aOff = offsets[e];
    Bh += (size_t)e * strideBTe;
    if (Csilu)      Csilu += (size_t)aOff * (N >> 1);
    else if (Ch16)  Ch16  += (size_t)aOff * N;
    else            C     += (size_t)aOff * N;
    if (wtpP) wtpP += aOff;
    if (rIdx) rIdx += aOff;
  }
  __shared__ u16 AtH[64*72];
  __shared__ u16 BtH[64*72];

  int tid = threadIdx.x;
  int wid = tid >> 6, lane = tid & 63;
  int lo16 = lane & 15, hi4 = lane >> 4;
  int m0 = blockIdx.y * 64, n0 = blockIdx.x * 64;
  int srow = tid >> 2, sseg = (tid & 3) * 16;

  int am = m0 + srow;
  int arow;
  if (counts) {
    int mm = (am < M_) ? am : (M_ - 1);
    arow = rIdx ? rIdx[mm] : (aOff + mm);
  } else {
    arow = am;
  }
  const u16* aPH = Ah + (size_t)arow * K;
  const u16* bPH = Bh + (size_t)(n0 + srow) * K;

  uint4 a0r, a1r, b0r, b1r;
  #define GLOAD(kb) { \
    a0r = *(const uint4*)(aPH + (kb) + sseg); a1r = *(const uint4*)(aPH + (kb) + sseg + 8); \
    b0r = *(const uint4*)(bPH + (kb) + sseg); b1r = *(const uint4*)(bPH + (kb) + sseg + 8); }
  #define GSTORE() { \
    *(uint4*)&AtH[srow*72 + sseg] = a0r; *(uint4*)&AtH[srow*72 + sseg + 8] = a1r; \
    *(uint4*)&BtH[srow*72 + sseg] = b0r; *(uint4*)&BtH[srow*72 + sseg + 8] = b1r; }

  f4v acc[4];
  #pragma unroll
  for (int j = 0; j < 4; ++j) { acc[j][0]=0.f; acc[j][1]=0.f; acc[j][2]=0.f; acc[j][3]=0.f; }

  GLOAD(0); GSTORE();
  for (int kb = 0; kb < K; kb += 64) {
    __syncthreads();                  // staged tile visible
    if (kb + 64 < K) GLOAD(kb + 64);  // prefetch next tile under this tile's MFMAs
    int ar = wid*16 + lo16;
    h8v ah0 = *(const h8v*)&AtH[ar*72 + 8*hi4];
    h8v ah1 = *(const h8v*)&AtH[ar*72 + 32 + 8*hi4];
    #pragma unroll
    for (int j = 0; j < 4; ++j) {
      int br = j*16 + lo16;
      h8v bh0 = *(const h8v*)&BtH[br*72 + 8*hi4];
      h8v bh1 = *(const h8v*)&BtH[br*72 + 32 + 8*hi4];
      acc[j] = mfma16h(ah0, bh0, acc[j]);
      acc[j] = mfma16h(ah1, bh1, acc[j]);
    }
    __syncthreads();                  // all waves done reading LDS
    if (kb + 64 < K) GSTORE();        // write next tile (vmcnt drained under MFMAs)
  }
  #undef GLOAD
  #undef GSTORE
  #pragma unroll
  for (int r = 0; r < 4; ++r) {
    int rg = m0 + wid*16 + 4*hi4 + r;
    if (rg < M_) {
      if (Csilu) {
        size_t rb = (size_t)rg * (N >> 1);
        #pragma unroll
        for (int j = 0; j < 4; ++j) {
          float own = acc[j][r];
          float oth = __shfl_xor(own, 1, 64);   // partner col (same hi4/rg: convergent)
          if ((lo16 & 1) == 0) {                // even col = gate
            float sg = own / (1.f + expf(-own));
            float res = sg * oth;
            if (wtpP) res *= wtpP[rg];
            int cg = n0 + j*16 + lo16;
            Csilu[rb + (cg >> 1)] = f2h(res);
          }
        }
      } else {
        size_t rb = (size_t)rg * N;
        #pragma unroll
        for (int j = 0; j < 4; ++j) {
          int cg = n0 + j*16 + lo16;
          float v = acc[j][r];
          if (resid) v += resid[rb + cg];
          if (Ch16) Ch16[rb + cg] = f2h(v);
          else      C[rb + cg] = v;
        }
      }
    }
  }
}

// ---------------- fused RoPE(Q) + RoPE(K) + V-transpose (fp16 src) ----------------
// blockIdx partition: [0,4096) rope Q, [4096,5120) rope K, [5120,7168) vtrans.
__global__ __launch_bounds__(256) void rope_vtrans_kernel(
    const u16* __restrict__ src,
    const float* __restrict__ fc, const float* __restrict__ fs,
    u16* __restrict__ qOut, u16* __restrict__ kOut, u16* __restrict__ vOut) {
  int blk = blockIdx.x;
  if (blk < 5120) {
    int NH, colOff; u16* outH; int base;
    if (blk < 4096) { NH = 16; colOff = 0; outH = qOut; base = blk; }
    else            { NH = 4;  colOff = 1024; outH = kOut; base = blk - 4096; }
    int idx = base * 256 + threadIdx.x;
    int i = idx & 31; int tmp = idx >> 5;
    int hh = tmp % NH; int bt = tmp / NH;
    if (bt >= 2048) return;
    int t = bt & 1023, b = bt >> 10;
    const u16* sp = src + (size_t)bt * 1536 + colOff + hh*64 + 2*i;
    float a = h2f(sp[0]), bb = h2f(sp[1]);
    float c = fc[t*32 + i], s = fs[t*32 + i];
    float o0 = a*c - bb*s, o1 = a*s + bb*c;
    size_t o = (((size_t)(b*NH + hh))*1024 + t)*64 + 2*i;
    outH[o] = f2h(o0); outH[o+1] = f2h(o1);
  } else {
    int idx = (blk - 5120) * 256 + threadIdx.x;
    if (idx >= 2*4*64*1024) return;
    int t = idx & 1023; int tmp = idx >> 10;
    int hd = tmp & 63; int kv = (tmp >> 6) & 3; int b = tmp >> 8;
    vOut[idx] = src[(size_t)(b*1024 + t) * 1536 + 1280 + kv*64 + hd];
  }
}

// ---------------- flash attention (causal, GQA, fp16) ----------------
// LDS-staged K/V; complement qb mapping for XCD causal balance; T14 async
// staging; base-2 softmax; diagonal-only masking; setprio around MFMA.
__global__ __launch_bounds__(256) void attn_kernel(
    const u16* __restrict__ Qh,
    const u16* __restrict__ Kh_,
    const u16* __restrict__ Vh_,
    u16* __restrict__ Oh) {
  int b = blockIdx.z, h = blockIdx.y;
  int qb = (b == 0) ? (int)blockIdx.x : (15 - (int)blockIdx.x);
  int kv = h >> 2;
  size_t qoff = ((size_t)(b*16 + h)) * 65536;
  size_t koff = ((size_t)(b*4 + kv)) * 65536;

  __shared__ u16 KtH[64*72], VtH[64*72];
  __shared__ u16 PtH[4][16*72];

  int tid = threadIdx.x, wid = tid >> 6, lane = tid & 63;
  int lo16 = lane & 15, hi4 = lane >> 4;
  int srow = tid >> 2, sseg = (tid & 3) * 16;

  int qrow = qb*64 + wid*16 + lo16;
  const u16* qbh_ = Qh + qoff + (size_t)qrow*64;
  h8v qh0 = *(const h8v*)(qbh_ + 8*hi4);
  h8v qh1 = *(const h8v*)(qbh_ + 32 + 8*hi4);

  const u16* Kh = Kh_ + koff;
  const u16* Vh = Vh_ + koff;

  uint4 kh0r, kh1r, vh0r, vh1r;
  #define LOADT(kb) { \
    const u16* kh = Kh + (size_t)((kb)*64 + srow)*64 + sseg; \
    const u16* vh = Vh + (size_t)srow*1024 + (kb)*64 + sseg; \
    kh0r = *(const uint4*)(kh); kh1r = *(const uint4*)(kh + 8); \
    vh0r = *(const uint4*)(vh); vh1r = *(const uint4*)(vh + 8); }
  #define STORET() { \
    *(uint4*)&KtH[srow*72 + sseg]     = kh0r; *(uint4*)&KtH[srow*72 + sseg + 8] = kh1r; \
    *(uint4*)&VtH[srow*72 + sseg]     = vh0r; *(uint4*)&VtH[srow*72 + sseg + 8] = vh1r; }

  f4v oacc[4];
  #pragma unroll
  for (int j = 0; j < 4; ++j) { oacc[j][0]=0.f; oacc[j][1]=0.f; oacc[j][2]=0.f; oacc[j][3]=0.f; }
  float mrow[4] = {-1e30f, -1e30f, -1e30f, -1e30f};
  float lrow[4] = {0.f, 0.f, 0.f, 0.f};
  int qmy = qb*64 + wid*16 + 4*hi4;
  u16* PwH = PtH[wid];

  const float SC = 0.125f * 1.44269504088896f;

  LOADT(0); STORET();
  for (int kblk = 0; kblk <= qb; ++kblk) {
    __syncthreads();
    if (kblk < qb) LOADT(kblk + 1);

    // ---- S = Q K^T ----
    f4v sfr[4];
    __builtin_amdgcn_s_setprio(1);
    #pragma unroll
    for (int j = 0; j < 4; ++j) {
      int kr = j*16 + lo16;
      h8v kh0 = *(const h8v*)&KtH[kr*72 + 8*hi4];
      h8v kh1 = *(const h8v*)&KtH[kr*72 + 32 + 8*hi4];
      f4v s; s[0]=0.f; s[1]=0.f; s[2]=0.f; s[3]=0.f;
      s = mfma16h(qh0, kh0, s);
      s = mfma16h(qh1, kh1, s);
      sfr[j] = s;
    }
    __builtin_amdgcn_s_setprio(0);

    // ---- online softmax (base-2); diagonal-only masking ----
    bool diag = (kblk == qb);
    float scl[4];
    #pragma unroll
    for (int r = 0; r < 4; ++r) {
      int qr = qmy + r;
      #pragma unroll
      for (int j = 0; j < 4; ++j) {
        float v = sfr[j][r] * SC;
        if (diag) {
          int kc = kblk*64 + j*16 + lo16;
          v = (kc > qr) ? -1e30f : v;
        }
        sfr[j][r] = v;
      }
      float mx = fmaxf(fmaxf(sfr[0][r], sfr[1][r]), fmaxf(sfr[2][r], sfr[3][r]));
      #pragma unroll
      for (int o = 1; o < 16; o <<= 1) mx = fmaxf(mx, __shfl_xor(mx, o, 64));
      float mnew = fmaxf(mrow[r], mx);
      scl[r] = exp2f(mrow[r] - mnew);
      mrow[r] = mnew;
      float sum = 0.f;
      #pragma unroll
      for (int j = 0; j < 4; ++j) {
        float pv = exp2f(sfr[j][r] - mnew);
        sfr[j][r] = pv;
        sum += pv;
      }
      #pragma unroll
      for (int o = 1; o < 16; o <<= 1) sum += __shfl_xor(sum, o, 64);
      lrow[r] = lrow[r] * scl[r] + sum;
    }
    #pragma unroll
    for (int j = 0; j < 4; ++j) {
      #pragma unroll
      for (int r = 0; r < 4; ++r) oacc[j][r] *= scl[r];
    }

    // ---- P transpose through per-wave LDS ----
    #pragma unroll
    for (int r = 0; r < 4; ++r) {
      #pragma unroll
      for (int j = 0; j < 4; ++j) {
        PwH[(4*hi4 + r)*72 + j*16 + lo16] = f2h(sfr[j][r]);
      }
    }
    asm volatile("s_waitcnt lgkmcnt(0)" ::: "memory");
    h8v ph0 = *(const h8v*)&PwH[lo16*72 + 8*hi4];
    h8v ph1 = *(const h8v*)&PwH[lo16*72 + 32 + 8*hi4];

    // ---- O += P V ----
    __builtin_amdgcn_s_setprio(1);
    #pragma unroll
    for (int j = 0; j < 4; ++j) {
      int vr = j*16 + lo16;
      h8v vh0 = *(const h8v*)&VtH[vr*72 + 8*hi4];
      h8v vh1 = *(const h8v*)&VtH[vr*72 + 32 + 8*hi4];
      oacc[j] = mfma16h(ph0, vh0, oacc[j]);
      oacc[j] = mfma16h(ph1, vh1, oacc[j]);
    }
    __builtin_amdgcn_s_setprio(0);

    __syncthreads();
    if (kblk < qb) STORET();
  }
  #undef LOADT
  #undef STORET

  #pragma unroll
  for (int r = 0; r < 4; ++r) {
    float inv = 1.f / lrow[r];
    int tq = qb*64 + wid*16 + 4*hi4 + r;
    size_t base = ((size_t)(b*1024 + tq))*1024 + h*64;
    #pragma unroll
    for (int j = 0; j < 4; ++j) {
      Oh[base + j*16 + lo16] = f2h(oacc[j][r] * inv);
    }
  }
}

// ---------------- router: logits(fp32) -> softmax -> top4 ----------------
// d-SPLIT structure (R11-proven): 4 groups x 256-d each, shfl_xor(32) +
// 4x32 LDS patch; block = 2 rows, grid 1024 = 4 blocks/CU. rw direct from L2.
__global__ __launch_bounds__(256) void router_kernel(const float* __restrict__ h2,
                                                     const float* __restrict__ rw,
                                                     int* __restrict__ topIdx, float* __restrict__ topW,
                                                     int* __restrict__ counts) {
  __shared__ float hs[2][1024];
  __shared__ float part[4][32];
  __shared__ int hist[32];
  int t = threadIdx.x;
  int row0 = blockIdx.x * 2;
  if (t < 32) hist[t] = 0;

  {
    const float4* hsrc = (const float4*)(h2 + (size_t)row0 * 1024);
    float4* hdst = (float4*)&hs[0][0];
    hdst[t] = hsrc[t];
    hdst[t + 256] = hsrc[t + 256];
  }
  __syncthreads();

  int e = t & 31, g = t >> 5;
  int r = g >> 2, q = g & 3;
  const float* hp = &hs[r][q*256];
  const float* rp = rw + (size_t)(q*256)*32 + e;
  float b0 = 0.f, b1 = 0.f, b2 = 0.f, b3 = 0.f;
  #pragma unroll 16
  for (int d = 0; d < 256; d += 4) {
    b0 += hp[d+0] * rp[(d+0)*32];
    b1 += hp[d+1] * rp[(d+1)*32];
    b2 += hp[d+2] * rp[(d+2)*32];
    b3 += hp[d+3] * rp[(d+3)*32];
  }
  float pq = (b0 + b1) + (b2 + b3);
  pq += __shfl_xor(pq, 32, 64);
  int w = t >> 6;
  if ((t & 63) < 32) part[w][e] = pq;
  __syncthreads();

  if ((w & 1) == 0 && (t & 63) < 32) {
    float lg = part[w][e] + part[w+1][e];
    float mx = lg;
    #pragma unroll
    for (int o = 1; o < 32; o <<= 1) mx = fmaxf(mx, __shfl_xor(mx, o, 64));
    float ex = expf(lg - mx);
    float sm = ex;
    #pragma unroll
    for (int o = 1; o < 32; o <<= 1) sm += __shfl_xor(sm, o, 64);
    float prob = ex / sm;

    float pv = prob; int pi = e;
    int myRow = row0 + (w >> 1);
    for (int k = 0; k < 4; ++k) {
      float bv = pv; int bi = pi;
      #pragma unroll
      for (int o = 1; o < 32; o <<= 1) {
        float ov = __shfl_xor(bv, o, 64); int oi = __shfl_xor(bi, o, 64);
        if (ov > bv || (ov == bv && oi < bi)) { bv = ov; bi = oi; }
      }
      if (e == 0) {
        topIdx[myRow*4 + k] = bi; topW[myRow*4 + k] = bv;
        atomicAdd(&hist[bi], 1);
      }
      if (pi == bi) pv = -1.f;
    }
  }
  __syncthreads();
  if (t < 32 && hist[t] > 0) atomicAdd(&counts[t], hist[t]);
}

// ---------------- scan + scatter fused (one block) ----------------
__global__ __launch_bounds__(256) void scan_scatter_kernel(
    const int* __restrict__ counts, int* __restrict__ offsets,
    const int* __restrict__ topIdx, const float* __restrict__ topW,
    int* __restrict__ rows, float* __restrict__ wtp, int* __restrict__ pslot) {
  __shared__ int cur[32];
  int t = threadIdx.x;
  if (t == 0) {
    int acc = 0;
    for (int e = 0; e < 32; ++e) { offsets[e] = acc; cur[e] = acc; acc += counts[e]; }
    offsets[32] = acc;
  }
  __syncthreads();
  for (int i = t; i < 8192; i += 256) {
    int e = topIdx[i];
    int slot = atomicAdd(&cur[e], 1);
    rows[slot] = i >> 2;
    wtp[slot] = topW[i];
    pslot[i] = slot;
  }
}

// ---------------- final: out = x1 + shared(fp16) + sum_k pairOut(fp16)[slot_k] ----------------
__global__ __launch_bounds__(256) void final_kernel(const float* __restrict__ x1, const u16* __restrict__ shOut,
                                                    const u16* __restrict__ pairOut, const int* __restrict__ pslot,
                                                    float* __restrict__ out) {
  int n = blockIdx.x;
  int t = threadIdx.x;
  int s0 = pslot[n*4], s1 = pslot[n*4+1], s2 = pslot[n*4+2], s3 = pslot[n*4+3];
  float4 a  = ((const float4*)(x1 + (size_t)n*1024))[t];
  ushort4 sh = ((const ushort4*)(shOut + (size_t)n*1024))[t];
  ushort4 p0 = ((const ushort4*)(pairOut + (size_t)s0*1024))[t];
  ushort4 p1 = ((const ushort4*)(pairOut + (size_t)s1*1024))[t];
  ushort4 p2 = ((const ushort4*)(pairOut + (size_t)s2*1024))[t];
  ushort4 p3 = ((const ushort4*)(pairOut + (size_t)s3*1024))[t];
  float4 o;
  o.x = a.x + h2f(sh.x) + h2f(p0.x) + h2f(p1.x) + h2f(p2.x) + h2f(p3.x);
  o.y = a.y + h2f(sh.y) + h2f(p0.y) + h2f(p1.y) + h2f(p2.y) + h2f(p3.y);
  o.z = a.z + h2f(sh.z) + h2f(p0.z) + h2f(p1.z) + h2f(p2.z) + h2f(p3.z);
  o.w = a.w + h2f(sh.w) + h2f(p0.w) + h2f(p1.w) + h2f(p2.w) + h2f(p3.w);
  ((float4*)(out + (size_t)n*1024))[t] = o;
}

// ---------------- host ----------------
extern "C" void kernel_launch(void* const* d_in, const int* in_sizes, int n_in,
                              void* d_out, int out_size, void* d_ws, size_t ws_size,
                              hipStream_t stream) {
  const float* x   = (const float*)d_in[0];
  const float* fc  = (const float*)d_in[1];
  const float* fs  = (const float*)d_in[2];
  const float* n1w = (const float*)d_in[3];
  const float* n2w = (const float*)d_in[4];
  const float* wq  = (const float*)d_in[5];
  const float* wk  = (const float*)d_in[6];
  const float* wv  = (const float*)d_in[7];
  const float* wo  = (const float*)d_in[8];
  const float* rw  = (const float*)d_in[9];
  const float* wg  = (const float*)d_in[10];
  const float* wu  = (const float*)d_in[11];
  const float* wd  = (const float*)d_in[12];
  const float* shg = (const float*)d_in[13];
  const float* shu = (const float*)d_in[14];
  const float* shd = (const float*)d_in[15];
  float* out = (float*)d_out;
  (void)in_sizes; (void)n_in; (void)out_size;

  char* p = (char*)d_ws;
  auto alloc = [&](size_t n) { char* r = p; p += (n + 255) & ~(size_t)255; return r; };

  u16* wqkvT  = (u16*)alloc((size_t)1536*1024*2);
  u16* woT    = (u16*)alloc((size_t)1024*1024*2);
  u16* shguT  = (u16*)alloc((size_t)1024*1024*2);   // INTERLEAVED [g0,u0,g1,u1,...][1024]
  u16* shdT   = (u16*)alloc((size_t)1024*512*2);
  u16* wguT   = (u16*)alloc((size_t)32*512*1024*2); // per-expert INTERLEAVED (g,u) rows
  u16* wdT    = (u16*)alloc((size_t)32*1024*256*2);
  u16* hH     = (u16*)alloc((size_t)2048*1024*2);
  float* x1   = (float*)alloc((size_t)2048*1024*4);
  float* h2f_ = (float*)alloc((size_t)2048*1024*4);
  u16* h2b    = (u16*)alloc((size_t)2048*1024*2);
  u16* actb   = (u16*)alloc((size_t)8192*256*2);
  u16* sactb  = (u16*)alloc((size_t)2048*512*2);
  u16* shOut  = (u16*)alloc((size_t)2048*1024*2);   // shared-down out (fp16)
  int* topIdx = (int*)alloc(2048*4*4);
  float* topW = (float*)alloc(2048*4*4);
  int* counts = (int*)alloc(32*4);
  int* offsets = (int*)alloc(33*4);
  int* rows   = (int*)alloc(8192*4);
  float* wtp  = (float*)alloc(8192*4);
  int* pslot  = (int*)alloc(8192*4);
  // alias region: qkv/rope/attention temporaries, later reused as pairOut (fp16, 16MB)
  char* regionStart = p;
  u16* qkvh = (u16*)alloc((size_t)2048*1536*2);     // qkv proj out (fp16)
  u16* qbh = (u16*)alloc((size_t)2048*1024*2);
  u16* kbh = (u16*)alloc((size_t)524288*2);
  u16* vth = (u16*)alloc((size_t)524288*2);
  u16* attnH = (u16*)alloc((size_t)2048*1024*2);
  u16* pairOut = (u16*)regionStart;
  // pairOut (8192*1024*2 = 16MB) must fit inside/after the region
  {
    size_t regionBytes = (size_t)8192*1024*2;
    if ((size_t)(p - regionStart) < regionBytes) p = regionStart + regionBytes;
  }

  size_t needed = (size_t)(p - (char*)d_ws);
  if (needed > ws_size) return;  // insufficient workspace; fail clean

  dim3 blk(256);
  // ONE prep dispatch: transposes (2 tiles/block, reg-prefetched) + rmsnorm1 + zero_counts
  prep_kernel<<<5633, blk, 0, stream>>>(
      wq, wk, wv, wo, shg, shu, shd, wg, wu, wd,
      wqkvT, woT, shguT, shdT, wguT, wdT,
      x, n1w, hH, counts);
  // fused QKV projection: [2048 x 1536] -> fp16
  gemm_kernel<<<dim3(24, 32), blk, 0, stream>>>(hH, wqkvT, nullptr, qkvh, nullptr, nullptr,
      nullptr, nullptr, nullptr, nullptr, 2048, 1536, 1024, 0);
  // fused RoPE(Q) + RoPE(K) + V-transpose (one dispatch)
  rope_vtrans_kernel<<<7168, blk, 0, stream>>>(qkvh, fc, fs, qbh, kbh, vth);
  // attention
  attn_kernel<<<dim3(16,16,2), blk, 0, stream>>>(qbh, kbh, vth, attnH);
  // output projection + residual (f32 out: residual stream fidelity)
  gemm_kernel<<<dim3(16, 32), blk, 0, stream>>>(attnH, woT, x1, nullptr, nullptr, nullptr,
      x, nullptr, nullptr, nullptr, 2048, 1024, 1024, 0);
  // norm2 -> fp32 (router) + fp16 (experts)
  rmsnorm_kernel<<<2048, blk, 0, stream>>>(x1, n2w, h2b, h2f_);
  // router + grouping
  router_kernel<<<1024, blk, 0, stream>>>(h2f_, rw, topIdx, topW, counts);
  scan_scatter_kernel<<<1, blk, 0, stream>>>(counts, offsets, topIdx, topW, rows, wtp, pslot);
  // shared MLP: fused gate+up GEMM with SILU epilogue -> sactb, then down
  gemm_kernel<<<dim3(16, 32), blk, 0, stream>>>(h2b, shguT, nullptr, nullptr, sactb, nullptr,
      nullptr, nullptr, nullptr, nullptr, 2048, 1024, 1024, 0);
  gemm_kernel<<<dim3(16, 32), blk, 0, stream>>>(sactb, shdT, nullptr, shOut, nullptr, nullptr,
      nullptr, nullptr, nullptr, nullptr, 2048, 1024, 512, 0);
  // MoE experts: grouped gate+up GEMM with SILU(+wtp) epilogue -> actb, then down
  gemm_kernel<<<dim3(8, 32, 32), blk, 0, stream>>>(h2b, wguT, nullptr, nullptr, actb, wtp,
      nullptr, rows, counts, offsets, 0, 512, 1024, 512*1024);
  gemm_kernel<<<dim3(16, 32, 32), blk, 0, stream>>>(actb, wdT, nullptr, pairOut, nullptr, nullptr,
      nullptr, nullptr, counts, offsets, 0, 1024, 256, 1024*256);
  // final residual + combine
  final_kernel<<<2048, blk, 0, stream>>>(x1, shOut, pairOut, pslot, out);
}

// Round 21
// 240.518 us; speedup vs baseline: 1.0103x; 1.0103x over previous
//
#include <hip/hip_runtime.h>

typedef unsigned short u16;
typedef _Float16 h8v __attribute__((ext_vector_type(8)));
typedef __attribute__((ext_vector_type(4))) float f4v;

#define DEV static __device__ __forceinline__

// f32 -> fp16 bits (RNE via hardware cvt)
DEV u16 f2h(float f) {
  union { _Float16 h; u16 u; } v; v.h = (_Float16)f; return v.u;
}
DEV float h2f(u16 u) {
  union { u16 u; _Float16 h; } v; v.u = u; return (float)v.h;
}

DEV f4v mfma16h(h8v a, h8v b, f4v c) {
  return __builtin_amdgcn_mfma_f32_16x16x32_f16(a, b, c, 0, 0, 0);
}

// ---------------- prep: ALL weight transposes + rmsnorm1 + zero_counts ----------------
// 64x64 tiles; float4 reads, uint4 fp16 writes (16B/lane). R19-proven config.
// BW-bound on mixed L3-read/HBM-write (~3.5 TB/s combined): vectorization
// (R16/R17) and latency-prefetch (R20) both nulled -> practical floor ~51us.
// gate/up pairs write INTERLEAVED (row 2c = gate col c, 2c+1 = up col c) so
// the gu-GEMM epilogue fuses silu via adjacent-lane partner exchange.
__global__ __launch_bounds__(256) void prep_kernel(
    const float* __restrict__ wq, const float* __restrict__ wk,
    const float* __restrict__ wv, const float* __restrict__ wo,
    const float* __restrict__ shg, const float* __restrict__ shu,
    const float* __restrict__ shd,
    const float* __restrict__ wg, const float* __restrict__ wu,
    const float* __restrict__ wd,
    u16* __restrict__ wqkvT, u16* __restrict__ woT, u16* __restrict__ shguT,
    u16* __restrict__ shdT, u16* __restrict__ wguT, u16* __restrict__ wdT,
    const float* __restrict__ x, const float* __restrict__ n1w,
    u16* __restrict__ hH, int* __restrict__ counts) {
  int blk = blockIdx.x;
  if (blk < 7168) {
    const float* in; u16* out; int R, C, gx, gy; long long ozs; int base;
    int rmul, radd;
    if (blk < 256)       { in=wq;  out=wqkvT;                    R=1024; C=1024; gx=16; gy=16; ozs=0;        base=0;    rmul=1; radd=0; }
    else if (blk < 320)  { in=wk;  out=wqkvT+(size_t)1024*1024;  R=1024; C=256;  gx=4;  gy=16; ozs=0;        base=256;  rmul=1; radd=0; }
    else if (blk < 384)  { in=wv;  out=wqkvT+(size_t)1280*1024;  R=1024; C=256;  gx=4;  gy=16; ozs=0;        base=320;  rmul=1; radd=0; }
    else if (blk < 640)  { in=wo;  out=woT;                      R=1024; C=1024; gx=16; gy=16; ozs=0;        base=384;  rmul=1; radd=0; }
    else if (blk < 768)  { in=shg; out=shguT;                    R=1024; C=512;  gx=8;  gy=16; ozs=0;        base=640;  rmul=2; radd=0; }
    else if (blk < 896)  { in=shu; out=shguT;                    R=1024; C=512;  gx=8;  gy=16; ozs=0;        base=768;  rmul=2; radd=1; }
    else if (blk < 1024) { in=shd; out=shdT;                     R=512;  C=1024; gx=16; gy=8;  ozs=0;        base=896;  rmul=1; radd=0; }
    else if (blk < 3072) { in=wg;  out=wguT;                     R=1024; C=256;  gx=4;  gy=16; ozs=512*1024; base=1024; rmul=2; radd=0; }
    else if (blk < 5120) { in=wu;  out=wguT;                     R=1024; C=256;  gx=4;  gy=16; ozs=512*1024; base=3072; rmul=2; radd=1; }
    else                 { in=wd;  out=wdT;                      R=256;  C=1024; gx=16; gy=4;  ozs=256*1024; base=5120; rmul=1; radd=0; }
    int i = blk - base;
    int bx = i % gx; int rem = i / gx; int by = rem % gy; int z = rem / gy;
    __shared__ float tile[64][65];
    const float* inp = in + (size_t)z * R * C;
    u16* op = out + (size_t)z * ozs;
    int c0 = bx * 64, r0 = by * 64;
    int tcol = (threadIdx.x & 15) * 4;
    int trow = threadIdx.x >> 4;         // 0..15
    #pragma unroll
    for (int p = 0; p < 4; ++p) {
      int row = trow + p*16;
      float4 v = *(const float4*)(inp + (size_t)(r0+row)*C + c0 + tcol);
      tile[row][tcol] = v.x; tile[row][tcol+1] = v.y;
      tile[row][tcol+2] = v.z; tile[row][tcol+3] = v.w;
    }
    __syncthreads();
    int tcol8 = (threadIdx.x & 7) * 8;
    int trow2 = threadIdx.x >> 3;        // 0..31
    #pragma unroll
    for (int p = 0; p < 2; ++p) {
      int c = trow2 + p*32;
      uint4 ov;
      ov.x = (unsigned)f2h(tile[tcol8+0][c]) | ((unsigned)f2h(tile[tcol8+1][c]) << 16);
      ov.y = (unsigned)f2h(tile[tcol8+2][c]) | ((unsigned)f2h(tile[tcol8+3][c]) << 16);
      ov.z = (unsigned)f2h(tile[tcol8+4][c]) | ((unsigned)f2h(tile[tcol8+5][c]) << 16);
      ov.w = (unsigned)f2h(tile[tcol8+6][c]) | ((unsigned)f2h(tile[tcol8+7][c]) << 16);
      *(uint4*)(op + (size_t)((c0+c)*rmul + radd)*R + r0 + tcol8) = ov;
    }
  } else if (blk < 9216) {
    // ---- rmsnorm1: x row -> fp16 hH row
    int n = blk - 7168;
    int t = threadIdx.x;
    const float* xr = x + (size_t)n * 1024;
    float4 v = ((const float4*)xr)[t];
    float ss = v.x*v.x + v.y*v.y + v.z*v.z + v.w*v.w;
    #pragma unroll
    for (int o = 1; o < 64; o <<= 1) ss += __shfl_xor(ss, o, 64);
    __shared__ float wsum[4];
    if ((t & 63) == 0) wsum[t >> 6] = ss;
    __syncthreads();
    float tot = wsum[0] + wsum[1] + wsum[2] + wsum[3];
    float rs = rsqrtf(tot * (1.0f/1024.0f) + 1e-6f);
    float4 wv4 = ((const float4*)n1w)[t];
    ushort4 oh = { f2h(v.x*rs*wv4.x), f2h(v.y*rs*wv4.y),
                   f2h(v.z*rs*wv4.z), f2h(v.w*rs*wv4.w) };
    ((ushort4*)(hH + (size_t)n*1024))[t] = oh;
  } else {
    if (threadIdx.x < 32) counts[threadIdx.x] = 0;
  }
}

// ---------------- rmsnorm (f32 in -> fp16 out [+ optional f32 out]) ----------------
__global__ __launch_bounds__(256) void rmsnorm_kernel(const float* __restrict__ xin,
                                                      const float* __restrict__ w,
                                                      u16* __restrict__ outH,
                                                      float* __restrict__ outF) {
  int n = blockIdx.x;
  int t = threadIdx.x;
  const float* xr = xin + (size_t)n * 1024;
  float4 v = ((const float4*)xr)[t];
  float ss = v.x*v.x + v.y*v.y + v.z*v.z + v.w*v.w;
  #pragma unroll
  for (int o = 1; o < 64; o <<= 1) ss += __shfl_xor(ss, o, 64);
  __shared__ float wsum[4];
  if ((t & 63) == 0) wsum[t >> 6] = ss;
  __syncthreads();
  float tot = wsum[0] + wsum[1] + wsum[2] + wsum[3];
  float rs = rsqrtf(tot * (1.0f/1024.0f) + 1e-6f);
  float4 wv = ((const float4*)w)[t];
  float o0 = v.x*rs*wv.x, o1 = v.y*rs*wv.y, o2 = v.z*rs*wv.z, o3 = v.w*rs*wv.w;
  if (outF) {
    float4 of = {o0, o1, o2, o3};
    ((float4*)(outF + (size_t)n*1024))[t] = of;
  }
  ushort4 oh = { f2h(o0), f2h(o1), f2h(o2), f2h(o3) };
  ((ushort4*)(outH + (size_t)n*1024))[t] = oh;
}

// ---------------- GEMM BM=64 BN=64 BK=64 (proven config, fp16): C = A x BT^T ----------------
// Tile growth (BM/BN/BK) loses to block count in this 2-barrier structure
// (3x confirmed). Epilogue variants: C f32(+resid) | Ch16 fp16 | Csilu fused
// silu(g)*u from interleaved (g,u) cols via shfl_xor(1), even lanes write.
__global__ __launch_bounds__(256) void gemm_kernel(
    const u16* __restrict__ Ah,
    const u16* __restrict__ Bh,
    float* __restrict__ C, u16* __restrict__ Ch16,
    u16* __restrict__ Csilu, const float* __restrict__ wtpP,
    const float* __restrict__ resid,
    const int* __restrict__ rowIdx, const int* __restrict__ counts,
    const int* __restrict__ offsets,
    int M, int N, int K, int strideBTe) {
  int M_ = M;
  const int* rIdx = rowIdx;
  int aOff = 0;
  if (counts) {
    int e = blockIdx.z;
    M_ = counts[e];
    if ((int)blockIdx.y * 64 >= M_) return;
    aOff = offsets[e];
    Bh += (size_t)e * strideBTe;
    if (Csilu)      Csilu += (size_t)aOff * (N >> 1);
    else if (Ch16)  Ch16  += (size_t)aOff * N;
    else            C     += (size_t)aOff * N;
    if (wtpP) wtpP += aOff;
    if (rIdx) rIdx += aOff;
  }
  __shared__ u16 AtH[64*72];
  __shared__ u16 BtH[64*72];

  int tid = threadIdx.x;
  int wid = tid >> 6, lane = tid & 63;
  int lo16 = lane & 15, hi4 = lane >> 4;
  int m0 = blockIdx.y * 64, n0 = blockIdx.x * 64;
  int srow = tid >> 2, sseg = (tid & 3) * 16;

  int am = m0 + srow;
  int arow;
  if (counts) {
    int mm = (am < M_) ? am : (M_ - 1);
    arow = rIdx ? rIdx[mm] : (aOff + mm);
  } else {
    arow = am;
  }
  const u16* aPH = Ah + (size_t)arow * K;
  const u16* bPH = Bh + (size_t)(n0 + srow) * K;

  uint4 a0r, a1r, b0r, b1r;
  #define GLOAD(kb) { \
    a0r = *(const uint4*)(aPH + (kb) + sseg); a1r = *(const uint4*)(aPH + (kb) + sseg + 8); \
    b0r = *(const uint4*)(bPH + (kb) + sseg); b1r = *(const uint4*)(bPH + (kb) + sseg + 8); }
  #define GSTORE() { \
    *(uint4*)&AtH[srow*72 + sseg] = a0r; *(uint4*)&AtH[srow*72 + sseg + 8] = a1r; \
    *(uint4*)&BtH[srow*72 + sseg] = b0r; *(uint4*)&BtH[srow*72 + sseg + 8] = b1r; }

  f4v acc[4];
  #pragma unroll
  for (int j = 0; j < 4; ++j) { acc[j][0]=0.f; acc[j][1]=0.f; acc[j][2]=0.f; acc[j][3]=0.f; }

  GLOAD(0); GSTORE();
  for (int kb = 0; kb < K; kb += 64) {
    __syncthreads();                  // staged tile visible
    if (kb + 64 < K) GLOAD(kb + 64);  // prefetch next tile under this tile's MFMAs
    int ar = wid*16 + lo16;
    h8v ah0 = *(const h8v*)&AtH[ar*72 + 8*hi4];
    h8v ah1 = *(const h8v*)&AtH[ar*72 + 32 + 8*hi4];
    #pragma unroll
    for (int j = 0; j < 4; ++j) {
      int br = j*16 + lo16;
      h8v bh0 = *(const h8v*)&BtH[br*72 + 8*hi4];
      h8v bh1 = *(const h8v*)&BtH[br*72 + 32 + 8*hi4];
      acc[j] = mfma16h(ah0, bh0, acc[j]);
      acc[j] = mfma16h(ah1, bh1, acc[j]);
    }
    __syncthreads();                  // all waves done reading LDS
    if (kb + 64 < K) GSTORE();        // write next tile (vmcnt drained under MFMAs)
  }
  #undef GLOAD
  #undef GSTORE
  #pragma unroll
  for (int r = 0; r < 4; ++r) {
    int rg = m0 + wid*16 + 4*hi4 + r;
    if (rg < M_) {
      if (Csilu) {
        size_t rb = (size_t)rg * (N >> 1);
        #pragma unroll
        for (int j = 0; j < 4; ++j) {
          float own = acc[j][r];
          float oth = __shfl_xor(own, 1, 64);   // partner col (same hi4/rg: convergent)
          if ((lo16 & 1) == 0) {                // even col = gate
            float sg = own / (1.f + expf(-own));
            float res = sg * oth;
            if (wtpP) res *= wtpP[rg];
            int cg = n0 + j*16 + lo16;
            Csilu[rb + (cg >> 1)] = f2h(res);
          }
        }
      } else {
        size_t rb = (size_t)rg * N;
        #pragma unroll
        for (int j = 0; j < 4; ++j) {
          int cg = n0 + j*16 + lo16;
          float v = acc[j][r];
          if (resid) v += resid[rb + cg];
          if (Ch16) Ch16[rb + cg] = f2h(v);
          else      C[rb + cg] = v;
        }
      }
    }
  }
}

// ---------------- fused RoPE(Q) + RoPE(K) + V-transpose (fp16 src) ----------------
// blockIdx partition: [0,4096) rope Q, [4096,5120) rope K, [5120,7168) vtrans.
__global__ __launch_bounds__(256) void rope_vtrans_kernel(
    const u16* __restrict__ src,
    const float* __restrict__ fc, const float* __restrict__ fs,
    u16* __restrict__ qOut, u16* __restrict__ kOut, u16* __restrict__ vOut) {
  int blk = blockIdx.x;
  if (blk < 5120) {
    int NH, colOff; u16* outH; int base;
    if (blk < 4096) { NH = 16; colOff = 0; outH = qOut; base = blk; }
    else            { NH = 4;  colOff = 1024; outH = kOut; base = blk - 4096; }
    int idx = base * 256 + threadIdx.x;
    int i = idx & 31; int tmp = idx >> 5;
    int hh = tmp % NH; int bt = tmp / NH;
    if (bt >= 2048) return;
    int t = bt & 1023, b = bt >> 10;
    const u16* sp = src + (size_t)bt * 1536 + colOff + hh*64 + 2*i;
    float a = h2f(sp[0]), bb = h2f(sp[1]);
    float c = fc[t*32 + i], s = fs[t*32 + i];
    float o0 = a*c - bb*s, o1 = a*s + bb*c;
    size_t o = (((size_t)(b*NH + hh))*1024 + t)*64 + 2*i;
    outH[o] = f2h(o0); outH[o+1] = f2h(o1);
  } else {
    int idx = (blk - 5120) * 256 + threadIdx.x;
    if (idx >= 2*4*64*1024) return;
    int t = idx & 1023; int tmp = idx >> 10;
    int hd = tmp & 63; int kv = (tmp >> 6) & 3; int b = tmp >> 8;
    vOut[idx] = src[(size_t)(b*1024 + t) * 1536 + 1280 + kv*64 + hd];
  }
}

// ---------------- flash attention (causal, GQA, fp16) ----------------
// LDS-staged K/V; complement qb mapping for XCD causal balance; T14 async
// staging; base-2 softmax; diagonal-only masking; setprio around MFMA.
__global__ __launch_bounds__(256) void attn_kernel(
    const u16* __restrict__ Qh,
    const u16* __restrict__ Kh_,
    const u16* __restrict__ Vh_,
    u16* __restrict__ Oh) {
  int b = blockIdx.z, h = blockIdx.y;
  int qb = (b == 0) ? (int)blockIdx.x : (15 - (int)blockIdx.x);
  int kv = h >> 2;
  size_t qoff = ((size_t)(b*16 + h)) * 65536;
  size_t koff = ((size_t)(b*4 + kv)) * 65536;

  __shared__ u16 KtH[64*72], VtH[64*72];
  __shared__ u16 PtH[4][16*72];

  int tid = threadIdx.x, wid = tid >> 6, lane = tid & 63;
  int lo16 = lane & 15, hi4 = lane >> 4;
  int srow = tid >> 2, sseg = (tid & 3) * 16;

  int qrow = qb*64 + wid*16 + lo16;
  const u16* qbh_ = Qh + qoff + (size_t)qrow*64;
  h8v qh0 = *(const h8v*)(qbh_ + 8*hi4);
  h8v qh1 = *(const h8v*)(qbh_ + 32 + 8*hi4);

  const u16* Kh = Kh_ + koff;
  const u16* Vh = Vh_ + koff;

  uint4 kh0r, kh1r, vh0r, vh1r;
  #define LOADT(kb) { \
    const u16* kh = Kh + (size_t)((kb)*64 + srow)*64 + sseg; \
    const u16* vh = Vh + (size_t)srow*1024 + (kb)*64 + sseg; \
    kh0r = *(const uint4*)(kh); kh1r = *(const uint4*)(kh + 8); \
    vh0r = *(const uint4*)(vh); vh1r = *(const uint4*)(vh + 8); }
  #define STORET() { \
    *(uint4*)&KtH[srow*72 + sseg]     = kh0r; *(uint4*)&KtH[srow*72 + sseg + 8] = kh1r; \
    *(uint4*)&VtH[srow*72 + sseg]     = vh0r; *(uint4*)&VtH[srow*72 + sseg + 8] = vh1r; }

  f4v oacc[4];
  #pragma unroll
  for (int j = 0; j < 4; ++j) { oacc[j][0]=0.f; oacc[j][1]=0.f; oacc[j][2]=0.f; oacc[j][3]=0.f; }
  float mrow[4] = {-1e30f, -1e30f, -1e30f, -1e30f};
  float lrow[4] = {0.f, 0.f, 0.f, 0.f};
  int qmy = qb*64 + wid*16 + 4*hi4;
  u16* PwH = PtH[wid];

  const float SC = 0.125f * 1.44269504088896f;

  LOADT(0); STORET();
  for (int kblk = 0; kblk <= qb; ++kblk) {
    __syncthreads();
    if (kblk < qb) LOADT(kblk + 1);

    // ---- S = Q K^T ----
    f4v sfr[4];
    __builtin_amdgcn_s_setprio(1);
    #pragma unroll
    for (int j = 0; j < 4; ++j) {
      int kr = j*16 + lo16;
      h8v kh0 = *(const h8v*)&KtH[kr*72 + 8*hi4];
      h8v kh1 = *(const h8v*)&KtH[kr*72 + 32 + 8*hi4];
      f4v s; s[0]=0.f; s[1]=0.f; s[2]=0.f; s[3]=0.f;
      s = mfma16h(qh0, kh0, s);
      s = mfma16h(qh1, kh1, s);
      sfr[j] = s;
    }
    __builtin_amdgcn_s_setprio(0);

    // ---- online softmax (base-2); diagonal-only masking ----
    bool diag = (kblk == qb);
    float scl[4];
    #pragma unroll
    for (int r = 0; r < 4; ++r) {
      int qr = qmy + r;
      #pragma unroll
      for (int j = 0; j < 4; ++j) {
        float v = sfr[j][r] * SC;
        if (diag) {
          int kc = kblk*64 + j*16 + lo16;
          v = (kc > qr) ? -1e30f : v;
        }
        sfr[j][r] = v;
      }
      float mx = fmaxf(fmaxf(sfr[0][r], sfr[1][r]), fmaxf(sfr[2][r], sfr[3][r]));
      #pragma unroll
      for (int o = 1; o < 16; o <<= 1) mx = fmaxf(mx, __shfl_xor(mx, o, 64));
      float mnew = fmaxf(mrow[r], mx);
      scl[r] = exp2f(mrow[r] - mnew);
      mrow[r] = mnew;
      float sum = 0.f;
      #pragma unroll
      for (int j = 0; j < 4; ++j) {
        float pv = exp2f(sfr[j][r] - mnew);
        sfr[j][r] = pv;
        sum += pv;
      }
      #pragma unroll
      for (int o = 1; o < 16; o <<= 1) sum += __shfl_xor(sum, o, 64);
      lrow[r] = lrow[r] * scl[r] + sum;
    }
    #pragma unroll
    for (int j = 0; j < 4; ++j) {
      #pragma unroll
      for (int r = 0; r < 4; ++r) oacc[j][r] *= scl[r];
    }

    // ---- P transpose through per-wave LDS ----
    #pragma unroll
    for (int r = 0; r < 4; ++r) {
      #pragma unroll
      for (int j = 0; j < 4; ++j) {
        PwH[(4*hi4 + r)*72 + j*16 + lo16] = f2h(sfr[j][r]);
      }
    }
    asm volatile("s_waitcnt lgkmcnt(0)" ::: "memory");
    h8v ph0 = *(const h8v*)&PwH[lo16*72 + 8*hi4];
    h8v ph1 = *(const h8v*)&PwH[lo16*72 + 32 + 8*hi4];

    // ---- O += P V ----
    __builtin_amdgcn_s_setprio(1);
    #pragma unroll
    for (int j = 0; j < 4; ++j) {
      int vr = j*16 + lo16;
      h8v vh0 = *(const h8v*)&VtH[vr*72 + 8*hi4];
      h8v vh1 = *(const h8v*)&VtH[vr*72 + 32 + 8*hi4];
      oacc[j] = mfma16h(ph0, vh0, oacc[j]);
      oacc[j] = mfma16h(ph1, vh1, oacc[j]);
    }
    __builtin_amdgcn_s_setprio(0);

    __syncthreads();
    if (kblk < qb) STORET();
  }
  #undef LOADT
  #undef STORET

  #pragma unroll
  for (int r = 0; r < 4; ++r) {
    float inv = 1.f / lrow[r];
    int tq = qb*64 + wid*16 + 4*hi4 + r;
    size_t base = ((size_t)(b*1024 + tq))*1024 + h*64;
    #pragma unroll
    for (int j = 0; j < 4; ++j) {
      Oh[base + j*16 + lo16] = f2h(oacc[j][r] * inv);
    }
  }
}

// ---------------- router: logits(fp32) -> softmax -> top4 ----------------
// d-SPLIT structure (R11-proven): 4 groups x 256-d each, shfl_xor(32) +
// 4x32 LDS patch; block = 2 rows, grid 1024 = 4 blocks/CU. rw direct from L2.
__global__ __launch_bounds__(256) void router_kernel(const float* __restrict__ h2,
                                                     const float* __restrict__ rw,
                                                     int* __restrict__ topIdx, float* __restrict__ topW,
                                                     int* __restrict__ counts) {
  __shared__ float hs[2][1024];
  __shared__ float part[4][32];
  __shared__ int hist[32];
  int t = threadIdx.x;
  int row0 = blockIdx.x * 2;
  if (t < 32) hist[t] = 0;

  {
    const float4* hsrc = (const float4*)(h2 + (size_t)row0 * 1024);
    float4* hdst = (float4*)&hs[0][0];
    hdst[t] = hsrc[t];
    hdst[t + 256] = hsrc[t + 256];
  }
  __syncthreads();

  int e = t & 31, g = t >> 5;
  int r = g >> 2, q = g & 3;
  const float* hp = &hs[r][q*256];
  const float* rp = rw + (size_t)(q*256)*32 + e;
  float b0 = 0.f, b1 = 0.f, b2 = 0.f, b3 = 0.f;
  #pragma unroll 16
  for (int d = 0; d < 256; d += 4) {
    b0 += hp[d+0] * rp[(d+0)*32];
    b1 += hp[d+1] * rp[(d+1)*32];
    b2 += hp[d+2] * rp[(d+2)*32];
    b3 += hp[d+3] * rp[(d+3)*32];
  }
  float pq = (b0 + b1) + (b2 + b3);
  pq += __shfl_xor(pq, 32, 64);
  int w = t >> 6;
  if ((t & 63) < 32) part[w][e] = pq;
  __syncthreads();

  if ((w & 1) == 0 && (t & 63) < 32) {
    float lg = part[w][e] + part[w+1][e];
    float mx = lg;
    #pragma unroll
    for (int o = 1; o < 32; o <<= 1) mx = fmaxf(mx, __shfl_xor(mx, o, 64));
    float ex = expf(lg - mx);
    float sm = ex;
    #pragma unroll
    for (int o = 1; o < 32; o <<= 1) sm += __shfl_xor(sm, o, 64);
    float prob = ex / sm;

    float pv = prob; int pi = e;
    int myRow = row0 + (w >> 1);
    for (int k = 0; k < 4; ++k) {
      float bv = pv; int bi = pi;
      #pragma unroll
      for (int o = 1; o < 32; o <<= 1) {
        float ov = __shfl_xor(bv, o, 64); int oi = __shfl_xor(bi, o, 64);
        if (ov > bv || (ov == bv && oi < bi)) { bv = ov; bi = oi; }
      }
      if (e == 0) {
        topIdx[myRow*4 + k] = bi; topW[myRow*4 + k] = bv;
        atomicAdd(&hist[bi], 1);
      }
      if (pi == bi) pv = -1.f;
    }
  }
  __syncthreads();
  if (t < 32 && hist[t] > 0) atomicAdd(&counts[t], hist[t]);
}

// ---------------- scan + scatter fused (one block) ----------------
__global__ __launch_bounds__(256) void scan_scatter_kernel(
    const int* __restrict__ counts, int* __restrict__ offsets,
    const int* __restrict__ topIdx, const float* __restrict__ topW,
    int* __restrict__ rows, float* __restrict__ wtp, int* __restrict__ pslot) {
  __shared__ int cur[32];
  int t = threadIdx.x;
  if (t == 0) {
    int acc = 0;
    for (int e = 0; e < 32; ++e) { offsets[e] = acc; cur[e] = acc; acc += counts[e]; }
    offsets[32] = acc;
  }
  __syncthreads();
  for (int i = t; i < 8192; i += 256) {
    int e = topIdx[i];
    int slot = atomicAdd(&cur[e], 1);
    rows[slot] = i >> 2;
    wtp[slot] = topW[i];
    pslot[i] = slot;
  }
}

// ---------------- final: out = x1 + shared(fp16) + sum_k pairOut(fp16)[slot_k] ----------------
__global__ __launch_bounds__(256) void final_kernel(const float* __restrict__ x1, const u16* __restrict__ shOut,
                                                    const u16* __restrict__ pairOut, const int* __restrict__ pslot,
                                                    float* __restrict__ out) {
  int n = blockIdx.x;
  int t = threadIdx.x;
  int s0 = pslot[n*4], s1 = pslot[n*4+1], s2 = pslot[n*4+2], s3 = pslot[n*4+3];
  float4 a  = ((const float4*)(x1 + (size_t)n*1024))[t];
  ushort4 sh = ((const ushort4*)(shOut + (size_t)n*1024))[t];
  ushort4 p0 = ((const ushort4*)(pairOut + (size_t)s0*1024))[t];
  ushort4 p1 = ((const ushort4*)(pairOut + (size_t)s1*1024))[t];
  ushort4 p2 = ((const ushort4*)(pairOut + (size_t)s2*1024))[t];
  ushort4 p3 = ((const ushort4*)(pairOut + (size_t)s3*1024))[t];
  float4 o;
  o.x = a.x + h2f(sh.x) + h2f(p0.x) + h2f(p1.x) + h2f(p2.x) + h2f(p3.x);
  o.y = a.y + h2f(sh.y) + h2f(p0.y) + h2f(p1.y) + h2f(p2.y) + h2f(p3.y);
  o.z = a.z + h2f(sh.z) + h2f(p0.z) + h2f(p1.z) + h2f(p2.z) + h2f(p3.z);
  o.w = a.w + h2f(sh.w) + h2f(p0.w) + h2f(p1.w) + h2f(p2.w) + h2f(p3.w);
  ((float4*)(out + (size_t)n*1024))[t] = o;
}

// ---------------- host ----------------
extern "C" void kernel_launch(void* const* d_in, const int* in_sizes, int n_in,
                              void* d_out, int out_size, void* d_ws, size_t ws_size,
                              hipStream_t stream) {
  const float* x   = (const float*)d_in[0];
  const float* fc  = (const float*)d_in[1];
  const float* fs  = (const float*)d_in[2];
  const float* n1w = (const float*)d_in[3];
  const float* n2w = (const float*)d_in[4];
  const float* wq  = (const float*)d_in[5];
  const float* wk  = (const float*)d_in[6];
  const float* wv  = (const float*)d_in[7];
  const float* wo  = (const float*)d_in[8];
  const float* rw  = (const float*)d_in[9];
  const float* wg  = (const float*)d_in[10];
  const float* wu  = (const float*)d_in[11];
  const float* wd  = (const float*)d_in[12];
  const float* shg = (const float*)d_in[13];
  const float* shu = (const float*)d_in[14];
  const float* shd = (const float*)d_in[15];
  float* out = (float*)d_out;
  (void)in_sizes; (void)n_in; (void)out_size;

  char* p = (char*)d_ws;
  auto alloc = [&](size_t n) { char* r = p; p += (n + 255) & ~(size_t)255; return r; };

  u16* wqkvT  = (u16*)alloc((size_t)1536*1024*2);
  u16* woT    = (u16*)alloc((size_t)1024*1024*2);
  u16* shguT  = (u16*)alloc((size_t)1024*1024*2);   // INTERLEAVED [g0,u0,g1,u1,...][1024]
  u16* shdT   = (u16*)alloc((size_t)1024*512*2);
  u16* wguT   = (u16*)alloc((size_t)32*512*1024*2); // per-expert INTERLEAVED (g,u) rows
  u16* wdT    = (u16*)alloc((size_t)32*1024*256*2);
  u16* hH     = (u16*)alloc((size_t)2048*1024*2);
  float* x1   = (float*)alloc((size_t)2048*1024*4);
  float* h2f_ = (float*)alloc((size_t)2048*1024*4);
  u16* h2b    = (u16*)alloc((size_t)2048*1024*2);
  u16* actb   = (u16*)alloc((size_t)8192*256*2);
  u16* sactb  = (u16*)alloc((size_t)2048*512*2);
  u16* shOut  = (u16*)alloc((size_t)2048*1024*2);   // shared-down out (fp16)
  int* topIdx = (int*)alloc(2048*4*4);
  float* topW = (float*)alloc(2048*4*4);
  int* counts = (int*)alloc(32*4);
  int* offsets = (int*)alloc(33*4);
  int* rows   = (int*)alloc(8192*4);
  float* wtp  = (float*)alloc(8192*4);
  int* pslot  = (int*)alloc(8192*4);
  // alias region: qkv/rope/attention temporaries, later reused as pairOut (fp16, 16MB)
  char* regionStart = p;
  u16* qkvh = (u16*)alloc((size_t)2048*1536*2);     // qkv proj out (fp16)
  u16* qbh = (u16*)alloc((size_t)2048*1024*2);
  u16* kbh = (u16*)alloc((size_t)524288*2);
  u16* vth = (u16*)alloc((size_t)524288*2);
  u16* attnH = (u16*)alloc((size_t)2048*1024*2);
  u16* pairOut = (u16*)regionStart;
  // pairOut (8192*1024*2 = 16MB) must fit inside/after the region
  {
    size_t regionBytes = (size_t)8192*1024*2;
    if ((size_t)(p - regionStart) < regionBytes) p = regionStart + regionBytes;
  }

  size_t needed = (size_t)(p - (char*)d_ws);
  if (needed > ws_size) return;  // insufficient workspace; fail clean

  dim3 blk(256);
  // ONE prep dispatch: all 10 weight transposes (gate/up interleaved) + rmsnorm1 + zero_counts
  prep_kernel<<<9217, blk, 0, stream>>>(
      wq, wk, wv, wo, shg, shu, shd, wg, wu, wd,
      wqkvT, woT, shguT, shdT, wguT, wdT,
      x, n1w, hH, counts);
  // fused QKV projection: [2048 x 1536] -> fp16
  gemm_kernel<<<dim3(24, 32), blk, 0, stream>>>(hH, wqkvT, nullptr, qkvh, nullptr, nullptr,
      nullptr, nullptr, nullptr, nullptr, 2048, 1536, 1024, 0);
  // fused RoPE(Q) + RoPE(K) + V-transpose (one dispatch)
  rope_vtrans_kernel<<<7168, blk, 0, stream>>>(qkvh, fc, fs, qbh, kbh, vth);
  // attention
  attn_kernel<<<dim3(16,16,2), blk, 0, stream>>>(qbh, kbh, vth, attnH);
  // output projection + residual (f32 out: residual stream fidelity)
  gemm_kernel<<<dim3(16, 32), blk, 0, stream>>>(attnH, woT, x1, nullptr, nullptr, nullptr,
      x, nullptr, nullptr, nullptr, 2048, 1024, 1024, 0);
  // norm2 -> fp32 (router) + fp16 (experts)
  rmsnorm_kernel<<<2048, blk, 0, stream>>>(x1, n2w, h2b, h2f_);
  // router + grouping
  router_kernel<<<1024, blk, 0, stream>>>(h2f_, rw, topIdx, topW, counts);
  scan_scatter_kernel<<<1, blk, 0, stream>>>(counts, offsets, topIdx, topW, rows, wtp, pslot);
  // shared MLP: fused gate+up GEMM with SILU epilogue -> sactb, then down
  gemm_kernel<<<dim3(16, 32), blk, 0, stream>>>(h2b, shguT, nullptr, nullptr, sactb, nullptr,
      nullptr, nullptr, nullptr, nullptr, 2048, 1024, 1024, 0);
  gemm_kernel<<<dim3(16, 32), blk, 0, stream>>>(sactb, shdT, nullptr, shOut, nullptr, nullptr,
      nullptr, nullptr, nullptr, nullptr, 2048, 1024, 512, 0);
  // MoE experts: grouped gate+up GEMM with SILU(+wtp) epilogue -> actb, then down
  gemm_kernel<<<dim3(8, 32, 32), blk, 0, stream>>>(h2b, wguT, nullptr, nullptr, actb, wtp,
      nullptr, rows, counts, offsets, 0, 512, 1024, 512*1024);
  gemm_kernel<<<dim3(16, 32, 32), blk, 0, stream>>>(actb, wdT, nullptr, pairOut, nullptr, nullptr,
      nullptr, nullptr, counts, offsets, 0, 1024, 256, 1024*256);
  // final residual + combine
  final_kernel<<<2048, blk, 0, stream>>>(x1, shOut, pairOut, pslot, out);
}

// Round 22
// 239.043 us; speedup vs baseline: 1.0166x; 1.0062x over previous
//
#include <hip/hip_runtime.h>

typedef unsigned short u16;
typedef _Float16 h8v __attribute__((ext_vector_type(8)));
typedef __attribute__((ext_vector_type(4))) float f4v;

#define DEV static __device__ __forceinline__

// f32 -> fp16 bits (RNE via hardware cvt)
DEV u16 f2h(float f) {
  union { _Float16 h; u16 u; } v; v.h = (_Float16)f; return v.u;
}
DEV float h2f(u16 u) {
  union { u16 u; _Float16 h; } v; v.u = u; return (float)v.h;
}

DEV f4v mfma16h(h8v a, h8v b, f4v c) {
  return __builtin_amdgcn_mfma_f32_16x16x32_f16(a, b, c, 0, 0, 0);
}

// ---------------- prep: ALL weight transposes + rmsnorm1 + zero_counts ----------------
// 64x64 tiles; float4 reads, uint4 fp16 writes (16B/lane). R19-proven config.
// BW-bound on mixed L3-read/HBM-write (~3.5 TB/s combined): vectorization
// (R16/R17) and latency-prefetch (R20) both nulled -> practical floor ~51us.
// gate/up pairs write INTERLEAVED (row 2c = gate col c, 2c+1 = up col c) so
// the gu-GEMM epilogue fuses silu via adjacent-lane partner exchange.
__global__ __launch_bounds__(256) void prep_kernel(
    const float* __restrict__ wq, const float* __restrict__ wk,
    const float* __restrict__ wv, const float* __restrict__ wo,
    const float* __restrict__ shg, const float* __restrict__ shu,
    const float* __restrict__ shd,
    const float* __restrict__ wg, const float* __restrict__ wu,
    const float* __restrict__ wd,
    u16* __restrict__ wqkvT, u16* __restrict__ woT, u16* __restrict__ shguT,
    u16* __restrict__ shdT, u16* __restrict__ wguT, u16* __restrict__ wdT,
    const float* __restrict__ x, const float* __restrict__ n1w,
    u16* __restrict__ hH, int* __restrict__ counts) {
  int blk = blockIdx.x;
  if (blk < 7168) {
    const float* in; u16* out; int R, C, gx, gy; long long ozs; int base;
    int rmul, radd;
    if (blk < 256)       { in=wq;  out=wqkvT;                    R=1024; C=1024; gx=16; gy=16; ozs=0;        base=0;    rmul=1; radd=0; }
    else if (blk < 320)  { in=wk;  out=wqkvT+(size_t)1024*1024;  R=1024; C=256;  gx=4;  gy=16; ozs=0;        base=256;  rmul=1; radd=0; }
    else if (blk < 384)  { in=wv;  out=wqkvT+(size_t)1280*1024;  R=1024; C=256;  gx=4;  gy=16; ozs=0;        base=320;  rmul=1; radd=0; }
    else if (blk < 640)  { in=wo;  out=woT;                      R=1024; C=1024; gx=16; gy=16; ozs=0;        base=384;  rmul=1; radd=0; }
    else if (blk < 768)  { in=shg; out=shguT;                    R=1024; C=512;  gx=8;  gy=16; ozs=0;        base=640;  rmul=2; radd=0; }
    else if (blk < 896)  { in=shu; out=shguT;                    R=1024; C=512;  gx=8;  gy=16; ozs=0;        base=768;  rmul=2; radd=1; }
    else if (blk < 1024) { in=shd; out=shdT;                     R=512;  C=1024; gx=16; gy=8;  ozs=0;        base=896;  rmul=1; radd=0; }
    else if (blk < 3072) { in=wg;  out=wguT;                     R=1024; C=256;  gx=4;  gy=16; ozs=512*1024; base=1024; rmul=2; radd=0; }
    else if (blk < 5120) { in=wu;  out=wguT;                     R=1024; C=256;  gx=4;  gy=16; ozs=512*1024; base=3072; rmul=2; radd=1; }
    else                 { in=wd;  out=wdT;                      R=256;  C=1024; gx=16; gy=4;  ozs=256*1024; base=5120; rmul=1; radd=0; }
    int i = blk - base;
    int bx = i % gx; int rem = i / gx; int by = rem % gy; int z = rem / gy;
    __shared__ float tile[64][65];
    const float* inp = in + (size_t)z * R * C;
    u16* op = out + (size_t)z * ozs;
    int c0 = bx * 64, r0 = by * 64;
    int tcol = (threadIdx.x & 15) * 4;
    int trow = threadIdx.x >> 4;         // 0..15
    #pragma unroll
    for (int p = 0; p < 4; ++p) {
      int row = trow + p*16;
      float4 v = *(const float4*)(inp + (size_t)(r0+row)*C + c0 + tcol);
      tile[row][tcol] = v.x; tile[row][tcol+1] = v.y;
      tile[row][tcol+2] = v.z; tile[row][tcol+3] = v.w;
    }
    __syncthreads();
    int tcol8 = (threadIdx.x & 7) * 8;
    int trow2 = threadIdx.x >> 3;        // 0..31
    #pragma unroll
    for (int p = 0; p < 2; ++p) {
      int c = trow2 + p*32;
      uint4 ov;
      ov.x = (unsigned)f2h(tile[tcol8+0][c]) | ((unsigned)f2h(tile[tcol8+1][c]) << 16);
      ov.y = (unsigned)f2h(tile[tcol8+2][c]) | ((unsigned)f2h(tile[tcol8+3][c]) << 16);
      ov.z = (unsigned)f2h(tile[tcol8+4][c]) | ((unsigned)f2h(tile[tcol8+5][c]) << 16);
      ov.w = (unsigned)f2h(tile[tcol8+6][c]) | ((unsigned)f2h(tile[tcol8+7][c]) << 16);
      *(uint4*)(op + (size_t)((c0+c)*rmul + radd)*R + r0 + tcol8) = ov;
    }
  } else if (blk < 9216) {
    // ---- rmsnorm1: x row -> fp16 hH row
    int n = blk - 7168;
    int t = threadIdx.x;
    const float* xr = x + (size_t)n * 1024;
    float4 v = ((const float4*)xr)[t];
    float ss = v.x*v.x + v.y*v.y + v.z*v.z + v.w*v.w;
    #pragma unroll
    for (int o = 1; o < 64; o <<= 1) ss += __shfl_xor(ss, o, 64);
    __shared__ float wsum[4];
    if ((t & 63) == 0) wsum[t >> 6] = ss;
    __syncthreads();
    float tot = wsum[0] + wsum[1] + wsum[2] + wsum[3];
    float rs = rsqrtf(tot * (1.0f/1024.0f) + 1e-6f);
    float4 wv4 = ((const float4*)n1w)[t];
    ushort4 oh = { f2h(v.x*rs*wv4.x), f2h(v.y*rs*wv4.y),
                   f2h(v.z*rs*wv4.z), f2h(v.w*rs*wv4.w) };
    ((ushort4*)(hH + (size_t)n*1024))[t] = oh;
  } else {
    if (threadIdx.x < 32) counts[threadIdx.x] = 0;
  }
}

// ---------------- rmsnorm (f32 in -> fp16 out [+ optional f32 out]) ----------------
__global__ __launch_bounds__(256) void rmsnorm_kernel(const float* __restrict__ xin,
                                                      const float* __restrict__ w,
                                                      u16* __restrict__ outH,
                                                      float* __restrict__ outF) {
  int n = blockIdx.x;
  int t = threadIdx.x;
  const float* xr = xin + (size_t)n * 1024;
  float4 v = ((const float4*)xr)[t];
  float ss = v.x*v.x + v.y*v.y + v.z*v.z + v.w*v.w;
  #pragma unroll
  for (int o = 1; o < 64; o <<= 1) ss += __shfl_xor(ss, o, 64);
  __shared__ float wsum[4];
  if ((t & 63) == 0) wsum[t >> 6] = ss;
  __syncthreads();
  float tot = wsum[0] + wsum[1] + wsum[2] + wsum[3];
  float rs = rsqrtf(tot * (1.0f/1024.0f) + 1e-6f);
  float4 wv = ((const float4*)w)[t];
  float o0 = v.x*rs*wv.x, o1 = v.y*rs*wv.y, o2 = v.z*rs*wv.z, o3 = v.w*rs*wv.w;
  if (outF) {
    float4 of = {o0, o1, o2, o3};
    ((float4*)(outF + (size_t)n*1024))[t] = of;
  }
  ushort4 oh = { f2h(o0), f2h(o1), f2h(o2), f2h(o3) };
  ((ushort4*)(outH + (size_t)n*1024))[t] = oh;
}

// ---------------- GEMM BM=64 BN=64 BK=64 (proven config, fp16): C = A x BT^T ----------------
// Tile growth (BM/BN/BK) loses to block count in this 2-barrier structure
// (3x confirmed). Epilogue variants:
//   C f32(+resid) | Ch16 fp16 | Csilu fused silu(g)*u (interleaved cols,
//   shfl_xor(1)) | Qr: fused RoPE(Q,K)+V-scatter for the QKV projection.
// Qr epilogue: cg<1024 -> Q rope, 1024..1280 -> K rope, >=1280 -> V transpose.
// RoPE pair (2i,2i+1) = adjacent lanes (cg parity == lane parity; pairs never
// cross the 16-lane group since head width 64 is 16-aligned). Computed from
// UNROUNDED f32 acc (previously from fp16-rounded qkvh -> strictly more
// accurate). Even lane: a*c - b*s; odd: a*s + b*c via shfl_xor(1).
__global__ __launch_bounds__(256) void gemm_kernel(
    const u16* __restrict__ Ah,
    const u16* __restrict__ Bh,
    float* __restrict__ C, u16* __restrict__ Ch16,
    u16* __restrict__ Csilu, const float* __restrict__ wtpP,
    u16* __restrict__ Qr, u16* __restrict__ Kr, u16* __restrict__ Vr,
    const float* __restrict__ fcP, const float* __restrict__ fsP,
    const float* __restrict__ resid,
    const int* __restrict__ rowIdx, const int* __restrict__ counts,
    const int* __restrict__ offsets,
    int M, int N, int K, int strideBTe) {
  int M_ = M;
  const int* rIdx = rowIdx;
  int aOff = 0;
  if (counts) {
    int e = blockIdx.z;
    M_ = counts[e];
    if ((int)blockIdx.y * 64 >= M_) return;
    aOff = offsets[e];
    Bh += (size_t)e * strideBTe;
    if (Csilu)      Csilu += (size_t)aOff * (N >> 1);
    else if (Ch16)  Ch16  += (size_t)aOff * N;
    else            C     += (size_t)aOff * N;
    if (wtpP) wtpP += aOff;
    if (rIdx) rIdx += aOff;
  }
  __shared__ u16 AtH[64*72];
  __shared__ u16 BtH[64*72];

  int tid = threadIdx.x;
  int wid = tid >> 6, lane = tid & 63;
  int lo16 = lane & 15, hi4 = lane >> 4;
  int m0 = blockIdx.y * 64, n0 = blockIdx.x * 64;
  int srow = tid >> 2, sseg = (tid & 3) * 16;

  int am = m0 + srow;
  int arow;
  if (counts) {
    int mm = (am < M_) ? am : (M_ - 1);
    arow = rIdx ? rIdx[mm] : (aOff + mm);
  } else {
    arow = am;
  }
  const u16* aPH = Ah + (size_t)arow * K;
  const u16* bPH = Bh + (size_t)(n0 + srow) * K;

  uint4 a0r, a1r, b0r, b1r;
  #define GLOAD(kb) { \
    a0r = *(const uint4*)(aPH + (kb) + sseg); a1r = *(const uint4*)(aPH + (kb) + sseg + 8); \
    b0r = *(const uint4*)(bPH + (kb) + sseg); b1r = *(const uint4*)(bPH + (kb) + sseg + 8); }
  #define GSTORE() { \
    *(uint4*)&AtH[srow*72 + sseg] = a0r; *(uint4*)&AtH[srow*72 + sseg + 8] = a1r; \
    *(uint4*)&BtH[srow*72 + sseg] = b0r; *(uint4*)&BtH[srow*72 + sseg + 8] = b1r; }

  f4v acc[4];
  #pragma unroll
  for (int j = 0; j < 4; ++j) { acc[j][0]=0.f; acc[j][1]=0.f; acc[j][2]=0.f; acc[j][3]=0.f; }

  GLOAD(0); GSTORE();
  for (int kb = 0; kb < K; kb += 64) {
    __syncthreads();                  // staged tile visible
    if (kb + 64 < K) GLOAD(kb + 64);  // prefetch next tile under this tile's MFMAs
    int ar = wid*16 + lo16;
    h8v ah0 = *(const h8v*)&AtH[ar*72 + 8*hi4];
    h8v ah1 = *(const h8v*)&AtH[ar*72 + 32 + 8*hi4];
    #pragma unroll
    for (int j = 0; j < 4; ++j) {
      int br = j*16 + lo16;
      h8v bh0 = *(const h8v*)&BtH[br*72 + 8*hi4];
      h8v bh1 = *(const h8v*)&BtH[br*72 + 32 + 8*hi4];
      acc[j] = mfma16h(ah0, bh0, acc[j]);
      acc[j] = mfma16h(ah1, bh1, acc[j]);
    }
    __syncthreads();                  // all waves done reading LDS
    if (kb + 64 < K) GSTORE();        // write next tile (vmcnt drained under MFMAs)
  }
  #undef GLOAD
  #undef GSTORE
  #pragma unroll
  for (int r = 0; r < 4; ++r) {
    int rg = m0 + wid*16 + 4*hi4 + r;
    if (rg < M_) {
      if (Qr) {
        // fused RoPE + V-scatter (QKV projection; M_=2048, all lanes active)
        int b = rg >> 10, t = rg & 1023;
        #pragma unroll
        for (int j = 0; j < 4; ++j) {
          int cg = n0 + j*16 + lo16;
          float own = acc[j][r];
          float oth = __shfl_xor(own, 1, 64);   // rope partner (same rg: convergent)
          if (cg < 1280) {
            int d = cg & 63;
            float c = fcP[t*32 + (d >> 1)];
            float s = fsP[t*32 + (d >> 1)];
            float o = ((lane & 1) == 0) ? (own*c - oth*s) : (oth*s + own*c);
            if (cg < 1024) {
              int hh = cg >> 6;
              Qr[(((size_t)(b*16 + hh))*1024 + t)*64 + d] = f2h(o);
            } else {
              int kv = (cg - 1024) >> 6;
              Kr[(((size_t)(b*4 + kv))*1024 + t)*64 + d] = f2h(o);
            }
          } else {
            int kv = (cg - 1280) >> 6;
            int hd = cg & 63;
            Vr[(((size_t)(b*4 + kv))*64 + hd)*1024 + t] = f2h(own);
          }
        }
      } else if (Csilu) {
        size_t rb = (size_t)rg * (N >> 1);
        #pragma unroll
        for (int j = 0; j < 4; ++j) {
          float own = acc[j][r];
          float oth = __shfl_xor(own, 1, 64);   // partner col (same hi4/rg: convergent)
          if ((lo16 & 1) == 0) {                // even col = gate
            float sg = own / (1.f + expf(-own));
            float res = sg * oth;
            if (wtpP) res *= wtpP[rg];
            int cg = n0 + j*16 + lo16;
            Csilu[rb + (cg >> 1)] = f2h(res);
          }
        }
      } else {
        size_t rb = (size_t)rg * N;
        #pragma unroll
        for (int j = 0; j < 4; ++j) {
          int cg = n0 + j*16 + lo16;
          float v = acc[j][r];
          if (resid) v += resid[rb + cg];
          if (Ch16) Ch16[rb + cg] = f2h(v);
          else      C[rb + cg] = v;
        }
      }
    }
  }
}

// ---------------- flash attention (causal, GQA, fp16) ----------------
// LDS-staged K/V; complement qb mapping for XCD causal balance; T14 async
// staging; base-2 softmax; diagonal-only masking; setprio around MFMA.
__global__ __launch_bounds__(256) void attn_kernel(
    const u16* __restrict__ Qh,
    const u16* __restrict__ Kh_,
    const u16* __restrict__ Vh_,
    u16* __restrict__ Oh) {
  int b = blockIdx.z, h = blockIdx.y;
  int qb = (b == 0) ? (int)blockIdx.x : (15 - (int)blockIdx.x);
  int kv = h >> 2;
  size_t qoff = ((size_t)(b*16 + h)) * 65536;
  size_t koff = ((size_t)(b*4 + kv)) * 65536;

  __shared__ u16 KtH[64*72], VtH[64*72];
  __shared__ u16 PtH[4][16*72];

  int tid = threadIdx.x, wid = tid >> 6, lane = tid & 63;
  int lo16 = lane & 15, hi4 = lane >> 4;
  int srow = tid >> 2, sseg = (tid & 3) * 16;

  int qrow = qb*64 + wid*16 + lo16;
  const u16* qbh_ = Qh + qoff + (size_t)qrow*64;
  h8v qh0 = *(const h8v*)(qbh_ + 8*hi4);
  h8v qh1 = *(const h8v*)(qbh_ + 32 + 8*hi4);

  const u16* Kh = Kh_ + koff;
  const u16* Vh = Vh_ + koff;

  uint4 kh0r, kh1r, vh0r, vh1r;
  #define LOADT(kb) { \
    const u16* kh = Kh + (size_t)((kb)*64 + srow)*64 + sseg; \
    const u16* vh = Vh + (size_t)srow*1024 + (kb)*64 + sseg; \
    kh0r = *(const uint4*)(kh); kh1r = *(const uint4*)(kh + 8); \
    vh0r = *(const uint4*)(vh); vh1r = *(const uint4*)(vh + 8); }
  #define STORET() { \
    *(uint4*)&KtH[srow*72 + sseg]     = kh0r; *(uint4*)&KtH[srow*72 + sseg + 8] = kh1r; \
    *(uint4*)&VtH[srow*72 + sseg]     = vh0r; *(uint4*)&VtH[srow*72 + sseg + 8] = vh1r; }

  f4v oacc[4];
  #pragma unroll
  for (int j = 0; j < 4; ++j) { oacc[j][0]=0.f; oacc[j][1]=0.f; oacc[j][2]=0.f; oacc[j][3]=0.f; }
  float mrow[4] = {-1e30f, -1e30f, -1e30f, -1e30f};
  float lrow[4] = {0.f, 0.f, 0.f, 0.f};
  int qmy = qb*64 + wid*16 + 4*hi4;
  u16* PwH = PtH[wid];

  const float SC = 0.125f * 1.44269504088896f;

  LOADT(0); STORET();
  for (int kblk = 0; kblk <= qb; ++kblk) {
    __syncthreads();
    if (kblk < qb) LOADT(kblk + 1);

    // ---- S = Q K^T ----
    f4v sfr[4];
    __builtin_amdgcn_s_setprio(1);
    #pragma unroll
    for (int j = 0; j < 4; ++j) {
      int kr = j*16 + lo16;
      h8v kh0 = *(const h8v*)&KtH[kr*72 + 8*hi4];
      h8v kh1 = *(const h8v*)&KtH[kr*72 + 32 + 8*hi4];
      f4v s; s[0]=0.f; s[1]=0.f; s[2]=0.f; s[3]=0.f;
      s = mfma16h(qh0, kh0, s);
      s = mfma16h(qh1, kh1, s);
      sfr[j] = s;
    }
    __builtin_amdgcn_s_setprio(0);

    // ---- online softmax (base-2); diagonal-only masking ----
    bool diag = (kblk == qb);
    float scl[4];
    #pragma unroll
    for (int r = 0; r < 4; ++r) {
      int qr = qmy + r;
      #pragma unroll
      for (int j = 0; j < 4; ++j) {
        float v = sfr[j][r] * SC;
        if (diag) {
          int kc = kblk*64 + j*16 + lo16;
          v = (kc > qr) ? -1e30f : v;
        }
        sfr[j][r] = v;
      }
      float mx = fmaxf(fmaxf(sfr[0][r], sfr[1][r]), fmaxf(sfr[2][r], sfr[3][r]));
      #pragma unroll
      for (int o = 1; o < 16; o <<= 1) mx = fmaxf(mx, __shfl_xor(mx, o, 64));
      float mnew = fmaxf(mrow[r], mx);
      scl[r] = exp2f(mrow[r] - mnew);
      mrow[r] = mnew;
      float sum = 0.f;
      #pragma unroll
      for (int j = 0; j < 4; ++j) {
        float pv = exp2f(sfr[j][r] - mnew);
        sfr[j][r] = pv;
        sum += pv;
      }
      #pragma unroll
      for (int o = 1; o < 16; o <<= 1) sum += __shfl_xor(sum, o, 64);
      lrow[r] = lrow[r] * scl[r] + sum;
    }
    #pragma unroll
    for (int j = 0; j < 4; ++j) {
      #pragma unroll
      for (int r = 0; r < 4; ++r) oacc[j][r] *= scl[r];
    }

    // ---- P transpose through per-wave LDS ----
    #pragma unroll
    for (int r = 0; r < 4; ++r) {
      #pragma unroll
      for (int j = 0; j < 4; ++j) {
        PwH[(4*hi4 + r)*72 + j*16 + lo16] = f2h(sfr[j][r]);
      }
    }
    asm volatile("s_waitcnt lgkmcnt(0)" ::: "memory");
    h8v ph0 = *(const h8v*)&PwH[lo16*72 + 8*hi4];
    h8v ph1 = *(const h8v*)&PwH[lo16*72 + 32 + 8*hi4];

    // ---- O += P V ----
    __builtin_amdgcn_s_setprio(1);
    #pragma unroll
    for (int j = 0; j < 4; ++j) {
      int vr = j*16 + lo16;
      h8v vh0 = *(const h8v*)&VtH[vr*72 + 8*hi4];
      h8v vh1 = *(const h8v*)&VtH[vr*72 + 32 + 8*hi4];
      oacc[j] = mfma16h(ph0, vh0, oacc[j]);
      oacc[j] = mfma16h(ph1, vh1, oacc[j]);
    }
    __builtin_amdgcn_s_setprio(0);

    __syncthreads();
    if (kblk < qb) STORET();
  }
  #undef LOADT
  #undef STORET

  #pragma unroll
  for (int r = 0; r < 4; ++r) {
    float inv = 1.f / lrow[r];
    int tq = qb*64 + wid*16 + 4*hi4 + r;
    size_t base = ((size_t)(b*1024 + tq))*1024 + h*64;
    #pragma unroll
    for (int j = 0; j < 4; ++j) {
      Oh[base + j*16 + lo16] = f2h(oacc[j][r] * inv);
    }
  }
}

// ---------------- router: logits(fp32) -> softmax -> top4 ----------------
// d-SPLIT structure (R11-proven): 4 groups x 256-d each, shfl_xor(32) +
// 4x32 LDS patch; block = 2 rows, grid 1024 = 4 blocks/CU. rw direct from L2.
__global__ __launch_bounds__(256) void router_kernel(const float* __restrict__ h2,
                                                     const float* __restrict__ rw,
                                                     int* __restrict__ topIdx, float* __restrict__ topW,
                                                     int* __restrict__ counts) {
  __shared__ float hs[2][1024];
  __shared__ float part[4][32];
  __shared__ int hist[32];
  int t = threadIdx.x;
  int row0 = blockIdx.x * 2;
  if (t < 32) hist[t] = 0;

  {
    const float4* hsrc = (const float4*)(h2 + (size_t)row0 * 1024);
    float4* hdst = (float4*)&hs[0][0];
    hdst[t] = hsrc[t];
    hdst[t + 256] = hsrc[t + 256];
  }
  __syncthreads();

  int e = t & 31, g = t >> 5;
  int r = g >> 2, q = g & 3;
  const float* hp = &hs[r][q*256];
  const float* rp = rw + (size_t)(q*256)*32 + e;
  float b0 = 0.f, b1 = 0.f, b2 = 0.f, b3 = 0.f;
  #pragma unroll 16
  for (int d = 0; d < 256; d += 4) {
    b0 += hp[d+0] * rp[(d+0)*32];
    b1 += hp[d+1] * rp[(d+1)*32];
    b2 += hp[d+2] * rp[(d+2)*32];
    b3 += hp[d+3] * rp[(d+3)*32];
  }
  float pq = (b0 + b1) + (b2 + b3);
  pq += __shfl_xor(pq, 32, 64);
  int w = t >> 6;
  if ((t & 63) < 32) part[w][e] = pq;
  __syncthreads();

  if ((w & 1) == 0 && (t & 63) < 32) {
    float lg = part[w][e] + part[w+1][e];
    float mx = lg;
    #pragma unroll
    for (int o = 1; o < 32; o <<= 1) mx = fmaxf(mx, __shfl_xor(mx, o, 64));
    float ex = expf(lg - mx);
    float sm = ex;
    #pragma unroll
    for (int o = 1; o < 32; o <<= 1) sm += __shfl_xor(sm, o, 64);
    float prob = ex / sm;

    float pv = prob; int pi = e;
    int myRow = row0 + (w >> 1);
    for (int k = 0; k < 4; ++k) {
      float bv = pv; int bi = pi;
      #pragma unroll
      for (int o = 1; o < 32; o <<= 1) {
        float ov = __shfl_xor(bv, o, 64); int oi = __shfl_xor(bi, o, 64);
        if (ov > bv || (ov == bv && oi < bi)) { bv = ov; bi = oi; }
      }
      if (e == 0) {
        topIdx[myRow*4 + k] = bi; topW[myRow*4 + k] = bv;
        atomicAdd(&hist[bi], 1);
      }
      if (pi == bi) pv = -1.f;
    }
  }
  __syncthreads();
  if (t < 32 && hist[t] > 0) atomicAdd(&counts[t], hist[t]);
}

// ---------------- scan + scatter fused (one block) ----------------
__global__ __launch_bounds__(256) void scan_scatter_kernel(
    const int* __restrict__ counts, int* __restrict__ offsets,
    const int* __restrict__ topIdx, const float* __restrict__ topW,
    int* __restrict__ rows, float* __restrict__ wtp, int* __restrict__ pslot) {
  __shared__ int cur[32];
  int t = threadIdx.x;
  if (t == 0) {
    int acc = 0;
    for (int e = 0; e < 32; ++e) { offsets[e] = acc; cur[e] = acc; acc += counts[e]; }
    offsets[32] = acc;
  }
  __syncthreads();
  for (int i = t; i < 8192; i += 256) {
    int e = topIdx[i];
    int slot = atomicAdd(&cur[e], 1);
    rows[slot] = i >> 2;
    wtp[slot] = topW[i];
    pslot[i] = slot;
  }
}

// ---------------- final: out = x1 + shared(fp16) + sum_k pairOut(fp16)[slot_k] ----------------
__global__ __launch_bounds__(256) void final_kernel(const float* __restrict__ x1, const u16* __restrict__ shOut,
                                                    const u16* __restrict__ pairOut, const int* __restrict__ pslot,
                                                    float* __restrict__ out) {
  int n = blockIdx.x;
  int t = threadIdx.x;
  int s0 = pslot[n*4], s1 = pslot[n*4+1], s2 = pslot[n*4+2], s3 = pslot[n*4+3];
  float4 a  = ((const float4*)(x1 + (size_t)n*1024))[t];
  ushort4 sh = ((const ushort4*)(shOut + (size_t)n*1024))[t];
  ushort4 p0 = ((const ushort4*)(pairOut + (size_t)s0*1024))[t];
  ushort4 p1 = ((const ushort4*)(pairOut + (size_t)s1*1024))[t];
  ushort4 p2 = ((const ushort4*)(pairOut + (size_t)s2*1024))[t];
  ushort4 p3 = ((const ushort4*)(pairOut + (size_t)s3*1024))[t];
  float4 o;
  o.x = a.x + h2f(sh.x) + h2f(p0.x) + h2f(p1.x) + h2f(p2.x) + h2f(p3.x);
  o.y = a.y + h2f(sh.y) + h2f(p0.y) + h2f(p1.y) + h2f(p2.y) + h2f(p3.y);
  o.z = a.z + h2f(sh.z) + h2f(p0.z) + h2f(p1.z) + h2f(p2.z) + h2f(p3.z);
  o.w = a.w + h2f(sh.w) + h2f(p0.w) + h2f(p1.w) + h2f(p2.w) + h2f(p3.w);
  ((float4*)(out + (size_t)n*1024))[t] = o;
}

// ---------------- host ----------------
extern "C" void kernel_launch(void* const* d_in, const int* in_sizes, int n_in,
                              void* d_out, int out_size, void* d_ws, size_t ws_size,
                              hipStream_t stream) {
  const float* x   = (const float*)d_in[0];
  const float* fc  = (const float*)d_in[1];
  const float* fs  = (const float*)d_in[2];
  const float* n1w = (const float*)d_in[3];
  const float* n2w = (const float*)d_in[4];
  const float* wq  = (const float*)d_in[5];
  const float* wk  = (const float*)d_in[6];
  const float* wv  = (const float*)d_in[7];
  const float* wo  = (const float*)d_in[8];
  const float* rw  = (const float*)d_in[9];
  const float* wg  = (const float*)d_in[10];
  const float* wu  = (const float*)d_in[11];
  const float* wd  = (const float*)d_in[12];
  const float* shg = (const float*)d_in[13];
  const float* shu = (const float*)d_in[14];
  const float* shd = (const float*)d_in[15];
  float* out = (float*)d_out;
  (void)in_sizes; (void)n_in; (void)out_size;

  char* p = (char*)d_ws;
  auto alloc = [&](size_t n) { char* r = p; p += (n + 255) & ~(size_t)255; return r; };

  u16* wqkvT  = (u16*)alloc((size_t)1536*1024*2);
  u16* woT    = (u16*)alloc((size_t)1024*1024*2);
  u16* shguT  = (u16*)alloc((size_t)1024*1024*2);   // INTERLEAVED [g0,u0,g1,u1,...][1024]
  u16* shdT   = (u16*)alloc((size_t)1024*512*2);
  u16* wguT   = (u16*)alloc((size_t)32*512*1024*2); // per-expert INTERLEAVED (g,u) rows
  u16* wdT    = (u16*)alloc((size_t)32*1024*256*2);
  u16* hH     = (u16*)alloc((size_t)2048*1024*2);
  float* x1   = (float*)alloc((size_t)2048*1024*4);
  float* h2f_ = (float*)alloc((size_t)2048*1024*4);
  u16* h2b    = (u16*)alloc((size_t)2048*1024*2);
  u16* actb   = (u16*)alloc((size_t)8192*256*2);
  u16* sactb  = (u16*)alloc((size_t)2048*512*2);
  u16* shOut  = (u16*)alloc((size_t)2048*1024*2);   // shared-down out (fp16)
  int* topIdx = (int*)alloc(2048*4*4);
  float* topW = (float*)alloc(2048*4*4);
  int* counts = (int*)alloc(32*4);
  int* offsets = (int*)alloc(33*4);
  int* rows   = (int*)alloc(8192*4);
  float* wtp  = (float*)alloc(8192*4);
  int* pslot  = (int*)alloc(8192*4);
  // alias region: attention temporaries, later reused as pairOut (fp16, 16MB)
  char* regionStart = p;
  u16* qbh = (u16*)alloc((size_t)2048*1024*2);
  u16* kbh = (u16*)alloc((size_t)524288*2);
  u16* vth = (u16*)alloc((size_t)524288*2);
  u16* attnH = (u16*)alloc((size_t)2048*1024*2);
  u16* pairOut = (u16*)regionStart;
  // pairOut (8192*1024*2 = 16MB) must fit inside/after the region
  {
    size_t regionBytes = (size_t)8192*1024*2;
    if ((size_t)(p - regionStart) < regionBytes) p = regionStart + regionBytes;
  }

  size_t needed = (size_t)(p - (char*)d_ws);
  if (needed > ws_size) return;  // insufficient workspace; fail clean

  dim3 blk(256);
  // ONE prep dispatch: all 10 weight transposes (gate/up interleaved) + rmsnorm1 + zero_counts
  prep_kernel<<<9217, blk, 0, stream>>>(
      wq, wk, wv, wo, shg, shu, shd, wg, wu, wd,
      wqkvT, woT, shguT, shdT, wguT, wdT,
      x, n1w, hH, counts);
  // fused QKV projection + RoPE(Q,K) + V-transpose: one GEMM, no qkvh round-trip
  gemm_kernel<<<dim3(24, 32), blk, 0, stream>>>(hH, wqkvT, nullptr, nullptr, nullptr, nullptr,
      qbh, kbh, vth, fc, fs,
      nullptr, nullptr, nullptr, nullptr, 2048, 1536, 1024, 0);
  // attention
  attn_kernel<<<dim3(16,16,2), blk, 0, stream>>>(qbh, kbh, vth, attnH);
  // output projection + residual (f32 out: residual stream fidelity)
  gemm_kernel<<<dim3(16, 32), blk, 0, stream>>>(attnH, woT, x1, nullptr, nullptr, nullptr,
      nullptr, nullptr, nullptr, nullptr, nullptr,
      x, nullptr, nullptr, nullptr, 2048, 1024, 1024, 0);
  // norm2 -> fp32 (router) + fp16 (experts)
  rmsnorm_kernel<<<2048, blk, 0, stream>>>(x1, n2w, h2b, h2f_);
  // router + grouping
  router_kernel<<<1024, blk, 0, stream>>>(h2f_, rw, topIdx, topW, counts);
  scan_scatter_kernel<<<1, blk, 0, stream>>>(counts, offsets, topIdx, topW, rows, wtp, pslot);
  // shared MLP: fused gate+up GEMM with SILU epilogue -> sactb, then down
  gemm_kernel<<<dim3(16, 32), blk, 0, stream>>>(h2b, shguT, nullptr, nullptr, sactb, nullptr,
      nullptr, nullptr, nullptr, nullptr, nullptr,
      nullptr, nullptr, nullptr, nullptr, 2048, 1024, 1024, 0);
  gemm_kernel<<<dim3(16, 32), blk, 0, stream>>>(sactb, shdT, nullptr, shOut, nullptr, nullptr,
      nullptr, nullptr, nullptr, nullptr, nullptr,
      nullptr, nullptr, nullptr, nullptr, 2048, 1024, 512, 0);
  // MoE experts: grouped gate+up GEMM with SILU(+wtp) epilogue -> actb, then down
  gemm_kernel<<<dim3(8, 32, 32), blk, 0, stream>>>(h2b, wguT, nullptr, nullptr, actb, wtp,
      nullptr, nullptr, nullptr, nullptr, nullptr,
      nullptr, rows, counts, offsets, 0, 512, 1024, 512*1024);
  gemm_kernel<<<dim3(16, 32, 32), blk, 0, stream>>>(actb, wdT, nullptr, pairOut, nullptr, nullptr,
      nullptr, nullptr, nullptr, nullptr, nullptr,
      nullptr, nullptr, counts, offsets, 0, 1024, 256, 1024*256);
  // final residual + combine
  final_kernel<<<2048, blk, 0, stream>>>(x1, shOut, pairOut, pslot, out);
}

// Round 23
// 220.793 us; speedup vs baseline: 1.1006x; 1.0827x over previous
//
#include <hip/hip_runtime.h>

typedef unsigned short u16;
typedef _Float16 h8v __attribute__((ext_vector_type(8)));
typedef __attribute__((ext_vector_type(4))) float f4v;

#define DEV static __device__ __forceinline__

// f32 -> fp16 bits (RNE via hardware cvt)
DEV u16 f2h(float f) {
  union { _Float16 h; u16 u; } v; v.h = (_Float16)f; return v.u;
}
DEV float h2f(u16 u) {
  union { u16 u; _Float16 h; } v; v.u = u; return (float)v.h;
}

DEV f4v mfma16h(h8v a, h8v b, f4v c) {
  return __builtin_amdgcn_mfma_f32_16x16x32_f16(a, b, c, 0, 0, 0);
}

// shared transpose-tile body (64x64, float4 reads, uint4 fp16 writes)
DEV void transpose_tile(const float* in, u16* out, int R, int C,
                        int bx, int by, int z, long long ozs,
                        int rmul, int radd, float (*tile)[65]) {
  const float* inp = in + (size_t)z * R * C;
  u16* op = out + (size_t)z * ozs;
  int c0 = bx * 64, r0 = by * 64;
  int tcol = (threadIdx.x & 15) * 4;
  int trow = threadIdx.x >> 4;         // 0..15
  #pragma unroll
  for (int p = 0; p < 4; ++p) {
    int row = trow + p*16;
    float4 v = *(const float4*)(inp + (size_t)(r0+row)*C + c0 + tcol);
    tile[row][tcol] = v.x; tile[row][tcol+1] = v.y;
    tile[row][tcol+2] = v.z; tile[row][tcol+3] = v.w;
  }
  __syncthreads();
  int tcol8 = (threadIdx.x & 7) * 8;
  int trow2 = threadIdx.x >> 3;        // 0..31
  #pragma unroll
  for (int p = 0; p < 2; ++p) {
    int c = trow2 + p*32;
    uint4 ov;
    ov.x = (unsigned)f2h(tile[tcol8+0][c]) | ((unsigned)f2h(tile[tcol8+1][c]) << 16);
    ov.y = (unsigned)f2h(tile[tcol8+2][c]) | ((unsigned)f2h(tile[tcol8+3][c]) << 16);
    ov.z = (unsigned)f2h(tile[tcol8+4][c]) | ((unsigned)f2h(tile[tcol8+5][c]) << 16);
    ov.w = (unsigned)f2h(tile[tcol8+6][c]) | ((unsigned)f2h(tile[tcol8+7][c]) << 16);
    *(uint4*)(op + (size_t)((c0+c)*rmul + radd)*R + r0 + tcol8) = ov;
  }
}

// ---------------- prep1: ONLY what gates the QKV GEMM ----------------
// wq/wk/wv transposes (384 tiles) + rmsnorm1 (2048) + zero_counts. The other
// 6784 weight tiles are deferred into the attn dispatch (attn_prep2): they
// are not consumed until after attention, and attn is latency-bound at ~12%
// occupancy -> the deferred transposes run in its idle CU/BW capacity.
__global__ __launch_bounds__(256) void prep1_kernel(
    const float* __restrict__ wq, const float* __restrict__ wk,
    const float* __restrict__ wv,
    u16* __restrict__ wqkvT,
    const float* __restrict__ x, const float* __restrict__ n1w,
    u16* __restrict__ hH, int* __restrict__ counts) {
  int blk = blockIdx.x;
  if (blk < 384) {
    const float* in; u16* out; int R, C, gx, gy; int base;
    if (blk < 256)      { in=wq; out=wqkvT;                   R=1024; C=1024; gx=16; gy=16; base=0; }
    else if (blk < 320) { in=wk; out=wqkvT+(size_t)1024*1024; R=1024; C=256;  gx=4;  gy=16; base=256; }
    else                { in=wv; out=wqkvT+(size_t)1280*1024; R=1024; C=256;  gx=4;  gy=16; base=320; }
    int i = blk - base;
    int bx = i % gx; int rem = i / gx; int by = rem % gy; int z = rem / gy;
    __shared__ float tile[64][65];
    transpose_tile(in, out, R, C, bx, by, z, 0, 1, 0, tile);
  } else if (blk < 2432) {
    // ---- rmsnorm1: x row -> fp16 hH row
    int n = blk - 384;
    int t = threadIdx.x;
    const float* xr = x + (size_t)n * 1024;
    float4 v = ((const float4*)xr)[t];
    float ss = v.x*v.x + v.y*v.y + v.z*v.z + v.w*v.w;
    #pragma unroll
    for (int o = 1; o < 64; o <<= 1) ss += __shfl_xor(ss, o, 64);
    __shared__ float wsum[4];
    if ((t & 63) == 0) wsum[t >> 6] = ss;
    __syncthreads();
    float tot = wsum[0] + wsum[1] + wsum[2] + wsum[3];
    float rs = rsqrtf(tot * (1.0f/1024.0f) + 1e-6f);
    float4 wv4 = ((const float4*)n1w)[t];
    ushort4 oh = { f2h(v.x*rs*wv4.x), f2h(v.y*rs*wv4.y),
                   f2h(v.z*rs*wv4.z), f2h(v.w*rs*wv4.w) };
    ((ushort4*)(hH + (size_t)n*1024))[t] = oh;
  } else {
    if (threadIdx.x < 32) counts[threadIdx.x] = 0;
  }
}

// ---------------- rmsnorm (f32 in -> fp16 out [+ optional f32 out]) ----------------
__global__ __launch_bounds__(256) void rmsnorm_kernel(const float* __restrict__ xin,
                                                      const float* __restrict__ w,
                                                      u16* __restrict__ outH,
                                                      float* __restrict__ outF) {
  int n = blockIdx.x;
  int t = threadIdx.x;
  const float* xr = xin + (size_t)n * 1024;
  float4 v = ((const float4*)xr)[t];
  float ss = v.x*v.x + v.y*v.y + v.z*v.z + v.w*v.w;
  #pragma unroll
  for (int o = 1; o < 64; o <<= 1) ss += __shfl_xor(ss, o, 64);
  __shared__ float wsum[4];
  if ((t & 63) == 0) wsum[t >> 6] = ss;
  __syncthreads();
  float tot = wsum[0] + wsum[1] + wsum[2] + wsum[3];
  float rs = rsqrtf(tot * (1.0f/1024.0f) + 1e-6f);
  float4 wv = ((const float4*)w)[t];
  float o0 = v.x*rs*wv.x, o1 = v.y*rs*wv.y, o2 = v.z*rs*wv.z, o3 = v.w*rs*wv.w;
  if (outF) {
    float4 of = {o0, o1, o2, o3};
    ((float4*)(outF + (size_t)n*1024))[t] = of;
  }
  ushort4 oh = { f2h(o0), f2h(o1), f2h(o2), f2h(o3) };
  ((ushort4*)(outH + (size_t)n*1024))[t] = oh;
}

// ---------------- GEMM BM=64 BN=64 BK=64 (proven config, fp16): C = A x BT^T ----------------
// Epilogues: C f32(+resid) | Ch16 fp16 | Csilu fused silu(g)*u | Qr fused
// RoPE(Q,K)+V-scatter (all R19/R22-proven).
__global__ __launch_bounds__(256) void gemm_kernel(
    const u16* __restrict__ Ah,
    const u16* __restrict__ Bh,
    float* __restrict__ C, u16* __restrict__ Ch16,
    u16* __restrict__ Csilu, const float* __restrict__ wtpP,
    u16* __restrict__ Qr, u16* __restrict__ Kr, u16* __restrict__ Vr,
    const float* __restrict__ fcP, const float* __restrict__ fsP,
    const float* __restrict__ resid,
    const int* __restrict__ rowIdx, const int* __restrict__ counts,
    const int* __restrict__ offsets,
    int M, int N, int K, int strideBTe) {
  int M_ = M;
  const int* rIdx = rowIdx;
  int aOff = 0;
  if (counts) {
    int e = blockIdx.z;
    M_ = counts[e];
    if ((int)blockIdx.y * 64 >= M_) return;
    aOff = offsets[e];
    Bh += (size_t)e * strideBTe;
    if (Csilu)      Csilu += (size_t)aOff * (N >> 1);
    else if (Ch16)  Ch16  += (size_t)aOff * N;
    else            C     += (size_t)aOff * N;
    if (wtpP) wtpP += aOff;
    if (rIdx) rIdx += aOff;
  }
  __shared__ u16 AtH[64*72];
  __shared__ u16 BtH[64*72];

  int tid = threadIdx.x;
  int wid = tid >> 6, lane = tid & 63;
  int lo16 = lane & 15, hi4 = lane >> 4;
  int m0 = blockIdx.y * 64, n0 = blockIdx.x * 64;
  int srow = tid >> 2, sseg = (tid & 3) * 16;

  int am = m0 + srow;
  int arow;
  if (counts) {
    int mm = (am < M_) ? am : (M_ - 1);
    arow = rIdx ? rIdx[mm] : (aOff + mm);
  } else {
    arow = am;
  }
  const u16* aPH = Ah + (size_t)arow * K;
  const u16* bPH = Bh + (size_t)(n0 + srow) * K;

  uint4 a0r, a1r, b0r, b1r;
  #define GLOAD(kb) { \
    a0r = *(const uint4*)(aPH + (kb) + sseg); a1r = *(const uint4*)(aPH + (kb) + sseg + 8); \
    b0r = *(const uint4*)(bPH + (kb) + sseg); b1r = *(const uint4*)(bPH + (kb) + sseg + 8); }
  #define GSTORE() { \
    *(uint4*)&AtH[srow*72 + sseg] = a0r; *(uint4*)&AtH[srow*72 + sseg + 8] = a1r; \
    *(uint4*)&BtH[srow*72 + sseg] = b0r; *(uint4*)&BtH[srow*72 + sseg + 8] = b1r; }

  f4v acc[4];
  #pragma unroll
  for (int j = 0; j < 4; ++j) { acc[j][0]=0.f; acc[j][1]=0.f; acc[j][2]=0.f; acc[j][3]=0.f; }

  GLOAD(0); GSTORE();
  for (int kb = 0; kb < K; kb += 64) {
    __syncthreads();                  // staged tile visible
    if (kb + 64 < K) GLOAD(kb + 64);  // prefetch next tile under this tile's MFMAs
    int ar = wid*16 + lo16;
    h8v ah0 = *(const h8v*)&AtH[ar*72 + 8*hi4];
    h8v ah1 = *(const h8v*)&AtH[ar*72 + 32 + 8*hi4];
    #pragma unroll
    for (int j = 0; j < 4; ++j) {
      int br = j*16 + lo16;
      h8v bh0 = *(const h8v*)&BtH[br*72 + 8*hi4];
      h8v bh1 = *(const h8v*)&BtH[br*72 + 32 + 8*hi4];
      acc[j] = mfma16h(ah0, bh0, acc[j]);
      acc[j] = mfma16h(ah1, bh1, acc[j]);
    }
    __syncthreads();                  // all waves done reading LDS
    if (kb + 64 < K) GSTORE();        // write next tile (vmcnt drained under MFMAs)
  }
  #undef GLOAD
  #undef GSTORE
  #pragma unroll
  for (int r = 0; r < 4; ++r) {
    int rg = m0 + wid*16 + 4*hi4 + r;
    if (rg < M_) {
      if (Qr) {
        // fused RoPE + V-scatter (QKV projection; M_=2048, all lanes active)
        int b = rg >> 10, t = rg & 1023;
        #pragma unroll
        for (int j = 0; j < 4; ++j) {
          int cg = n0 + j*16 + lo16;
          float own = acc[j][r];
          float oth = __shfl_xor(own, 1, 64);   // rope partner (same rg: convergent)
          if (cg < 1280) {
            int d = cg & 63;
            float c = fcP[t*32 + (d >> 1)];
            float s = fsP[t*32 + (d >> 1)];
            float o = ((lane & 1) == 0) ? (own*c - oth*s) : (oth*s + own*c);
            if (cg < 1024) {
              int hh = cg >> 6;
              Qr[(((size_t)(b*16 + hh))*1024 + t)*64 + d] = f2h(o);
            } else {
              int kv = (cg - 1024) >> 6;
              Kr[(((size_t)(b*4 + kv))*1024 + t)*64 + d] = f2h(o);
            }
          } else {
            int kv = (cg - 1280) >> 6;
            int hd = cg & 63;
            Vr[(((size_t)(b*4 + kv))*64 + hd)*1024 + t] = f2h(own);
          }
        }
      } else if (Csilu) {
        size_t rb = (size_t)rg * (N >> 1);
        #pragma unroll
        for (int j = 0; j < 4; ++j) {
          float own = acc[j][r];
          float oth = __shfl_xor(own, 1, 64);   // partner col (same hi4/rg: convergent)
          if ((lo16 & 1) == 0) {                // even col = gate
            float sg = own / (1.f + expf(-own));
            float res = sg * oth;
            if (wtpP) res *= wtpP[rg];
            int cg = n0 + j*16 + lo16;
            Csilu[rb + (cg >> 1)] = f2h(res);
          }
        }
      } else {
        size_t rb = (size_t)rg * N;
        #pragma unroll
        for (int j = 0; j < 4; ++j) {
          int cg = n0 + j*16 + lo16;
          float v = acc[j][r];
          if (resid) v += resid[rb + cg];
          if (Ch16) Ch16[rb + cg] = f2h(v);
          else      C[rb + cg] = v;
        }
      }
    }
  }
}

// ---------------- attn (blocks 0..511) + deferred weight transposes (512..7295) ----------------
// attn path is byte-identical (same linear block decode -> same XCD mapping).
// Transpose blocks fill attn's idle CU/BW capacity (attn is latency-bound at
// ~12% occupancy); their outputs (woT/shguT/shdT/wguT/wdT) are consumed only
// by later dispatches. LDS: 27648 B union (attn footprint; transpose uses 16.6K).
__global__ __launch_bounds__(256) void attn_prep2_kernel(
    const u16* __restrict__ Qh,
    const u16* __restrict__ Kh_,
    const u16* __restrict__ Vh_,
    u16* __restrict__ Oh,
    const float* __restrict__ wo, const float* __restrict__ shg,
    const float* __restrict__ shu, const float* __restrict__ shd,
    const float* __restrict__ wg, const float* __restrict__ wu,
    const float* __restrict__ wd,
    u16* __restrict__ woT, u16* __restrict__ shguT, u16* __restrict__ shdT,
    u16* __restrict__ wguT, u16* __restrict__ wdT) {
  __shared__ float smemF[6912];   // 27648 B union
  int blk = blockIdx.x;
  if (blk >= 512) {
    // ---- deferred transpose path ----
    int t = blk - 512;
    const float* in; u16* out; int R, C, gx, gy; long long ozs; int base;
    int rmul, radd;
    if (t < 256)       { in=wo;  out=woT;   R=1024; C=1024; gx=16; gy=16; ozs=0;        base=0;    rmul=1; radd=0; }
    else if (t < 384)  { in=shg; out=shguT; R=1024; C=512;  gx=8;  gy=16; ozs=0;        base=256;  rmul=2; radd=0; }
    else if (t < 512)  { in=shu; out=shguT; R=1024; C=512;  gx=8;  gy=16; ozs=0;        base=384;  rmul=2; radd=1; }
    else if (t < 640)  { in=shd; out=shdT;  R=512;  C=1024; gx=16; gy=8;  ozs=0;        base=512;  rmul=1; radd=0; }
    else if (t < 2688) { in=wg;  out=wguT;  R=1024; C=256;  gx=4;  gy=16; ozs=512*1024; base=640;  rmul=2; radd=0; }
    else if (t < 4736) { in=wu;  out=wguT;  R=1024; C=256;  gx=4;  gy=16; ozs=512*1024; base=2688; rmul=2; radd=1; }
    else               { in=wd;  out=wdT;   R=256;  C=1024; gx=16; gy=4;  ozs=256*1024; base=4736; rmul=1; radd=0; }
    int i = t - base;
    int bx = i % gx; int rem = i / gx; int by = rem % gy; int z = rem / gy;
    transpose_tile(in, out, R, C, bx, by, z, ozs, rmul, radd,
                   (float(*)[65])smemF);
    return;
  }
  // ---- attn path (decode preserves old dim3(16,16,2) linear order) ----
  int xq = blk & 15, h = (blk >> 4) & 15, b = blk >> 8;
  int qb = (b == 0) ? xq : (15 - xq);
  int kv = h >> 2;
  size_t qoff = ((size_t)(b*16 + h)) * 65536;
  size_t koff = ((size_t)(b*4 + kv)) * 65536;

  u16* KtH = (u16*)smemF;            // 64*72 u16
  u16* VtH = (u16*)smemF + 4608;     // 64*72 u16
  u16* PtH = (u16*)smemF + 9216;     // 4 x 16*72 u16

  int tid = threadIdx.x, wid = tid >> 6, lane = tid & 63;
  int lo16 = lane & 15, hi4 = lane >> 4;
  int srow = tid >> 2, sseg = (tid & 3) * 16;

  int qrow = qb*64 + wid*16 + lo16;
  const u16* qbh_ = Qh + qoff + (size_t)qrow*64;
  h8v qh0 = *(const h8v*)(qbh_ + 8*hi4);
  h8v qh1 = *(const h8v*)(qbh_ + 32 + 8*hi4);

  const u16* Kh = Kh_ + koff;
  const u16* Vh = Vh_ + koff;

  uint4 kh0r, kh1r, vh0r, vh1r;
  #define LOADT(kb) { \
    const u16* kh = Kh + (size_t)((kb)*64 + srow)*64 + sseg; \
    const u16* vh = Vh + (size_t)srow*1024 + (kb)*64 + sseg; \
    kh0r = *(const uint4*)(kh); kh1r = *(const uint4*)(kh + 8); \
    vh0r = *(const uint4*)(vh); vh1r = *(const uint4*)(vh + 8); }
  #define STORET() { \
    *(uint4*)&KtH[srow*72 + sseg]     = kh0r; *(uint4*)&KtH[srow*72 + sseg + 8] = kh1r; \
    *(uint4*)&VtH[srow*72 + sseg]     = vh0r; *(uint4*)&VtH[srow*72 + sseg + 8] = vh1r; }

  f4v oacc[4];
  #pragma unroll
  for (int j = 0; j < 4; ++j) { oacc[j][0]=0.f; oacc[j][1]=0.f; oacc[j][2]=0.f; oacc[j][3]=0.f; }
  float mrow[4] = {-1e30f, -1e30f, -1e30f, -1e30f};
  float lrow[4] = {0.f, 0.f, 0.f, 0.f};
  int qmy = qb*64 + wid*16 + 4*hi4;
  u16* PwH = PtH + wid*1152;

  const float SC = 0.125f * 1.44269504088896f;

  LOADT(0); STORET();
  for (int kblk = 0; kblk <= qb; ++kblk) {
    __syncthreads();
    if (kblk < qb) LOADT(kblk + 1);

    // ---- S = Q K^T ----
    f4v sfr[4];
    __builtin_amdgcn_s_setprio(1);
    #pragma unroll
    for (int j = 0; j < 4; ++j) {
      int kr = j*16 + lo16;
      h8v kh0 = *(const h8v*)&KtH[kr*72 + 8*hi4];
      h8v kh1 = *(const h8v*)&KtH[kr*72 + 32 + 8*hi4];
      f4v s; s[0]=0.f; s[1]=0.f; s[2]=0.f; s[3]=0.f;
      s = mfma16h(qh0, kh0, s);
      s = mfma16h(qh1, kh1, s);
      sfr[j] = s;
    }
    __builtin_amdgcn_s_setprio(0);

    // ---- online softmax (base-2); diagonal-only masking ----
    bool diag = (kblk == qb);
    float scl[4];
    #pragma unroll
    for (int r = 0; r < 4; ++r) {
      int qr = qmy + r;
      #pragma unroll
      for (int j = 0; j < 4; ++j) {
        float v = sfr[j][r] * SC;
        if (diag) {
          int kc = kblk*64 + j*16 + lo16;
          v = (kc > qr) ? -1e30f : v;
        }
        sfr[j][r] = v;
      }
      float mx = fmaxf(fmaxf(sfr[0][r], sfr[1][r]), fmaxf(sfr[2][r], sfr[3][r]));
      #pragma unroll
      for (int o = 1; o < 16; o <<= 1) mx = fmaxf(mx, __shfl_xor(mx, o, 64));
      float mnew = fmaxf(mrow[r], mx);
      scl[r] = exp2f(mrow[r] - mnew);
      mrow[r] = mnew;
      float sum = 0.f;
      #pragma unroll
      for (int j = 0; j < 4; ++j) {
        float pv = exp2f(sfr[j][r] - mnew);
        sfr[j][r] = pv;
        sum += pv;
      }
      #pragma unroll
      for (int o = 1; o < 16; o <<= 1) sum += __shfl_xor(sum, o, 64);
      lrow[r] = lrow[r] * scl[r] + sum;
    }
    #pragma unroll
    for (int j = 0; j < 4; ++j) {
      #pragma unroll
      for (int r = 0; r < 4; ++r) oacc[j][r] *= scl[r];
    }

    // ---- P transpose through per-wave LDS ----
    #pragma unroll
    for (int r = 0; r < 4; ++r) {
      #pragma unroll
      for (int j = 0; j < 4; ++j) {
        PwH[(4*hi4 + r)*72 + j*16 + lo16] = f2h(sfr[j][r]);
      }
    }
    asm volatile("s_waitcnt lgkmcnt(0)" ::: "memory");
    h8v ph0 = *(const h8v*)&PwH[lo16*72 + 8*hi4];
    h8v ph1 = *(const h8v*)&PwH[lo16*72 + 32 + 8*hi4];

    // ---- O += P V ----
    __builtin_amdgcn_s_setprio(1);
    #pragma unroll
    for (int j = 0; j < 4; ++j) {
      int vr = j*16 + lo16;
      h8v vh0 = *(const h8v*)&VtH[vr*72 + 8*hi4];
      h8v vh1 = *(const h8v*)&VtH[vr*72 + 32 + 8*hi4];
      oacc[j] = mfma16h(ph0, vh0, oacc[j]);
      oacc[j] = mfma16h(ph1, vh1, oacc[j]);
    }
    __builtin_amdgcn_s_setprio(0);

    __syncthreads();
    if (kblk < qb) STORET();
  }
  #undef LOADT
  #undef STORET

  #pragma unroll
  for (int r = 0; r < 4; ++r) {
    float inv = 1.f / lrow[r];
    int tq = qb*64 + wid*16 + 4*hi4 + r;
    size_t base = ((size_t)(b*1024 + tq))*1024 + h*64;
    #pragma unroll
    for (int j = 0; j < 4; ++j) {
      Oh[base + j*16 + lo16] = f2h(oacc[j][r] * inv);
    }
  }
}

// ---------------- router: logits(fp32) -> softmax -> top4 ----------------
// d-SPLIT structure (R11-proven): 4 groups x 256-d each, shfl_xor(32) +
// 4x32 LDS patch; block = 2 rows, grid 1024 = 4 blocks/CU. rw direct from L2.
__global__ __launch_bounds__(256) void router_kernel(const float* __restrict__ h2,
                                                     const float* __restrict__ rw,
                                                     int* __restrict__ topIdx, float* __restrict__ topW,
                                                     int* __restrict__ counts) {
  __shared__ float hs[2][1024];
  __shared__ float part[4][32];
  __shared__ int hist[32];
  int t = threadIdx.x;
  int row0 = blockIdx.x * 2;
  if (t < 32) hist[t] = 0;

  {
    const float4* hsrc = (const float4*)(h2 + (size_t)row0 * 1024);
    float4* hdst = (float4*)&hs[0][0];
    hdst[t] = hsrc[t];
    hdst[t + 256] = hsrc[t + 256];
  }
  __syncthreads();

  int e = t & 31, g = t >> 5;
  int r = g >> 2, q = g & 3;
  const float* hp = &hs[r][q*256];
  const float* rp = rw + (size_t)(q*256)*32 + e;
  float b0 = 0.f, b1 = 0.f, b2 = 0.f, b3 = 0.f;
  #pragma unroll 16
  for (int d = 0; d < 256; d += 4) {
    b0 += hp[d+0] * rp[(d+0)*32];
    b1 += hp[d+1] * rp[(d+1)*32];
    b2 += hp[d+2] * rp[(d+2)*32];
    b3 += hp[d+3] * rp[(d+3)*32];
  }
  float pq = (b0 + b1) + (b2 + b3);
  pq += __shfl_xor(pq, 32, 64);
  int w = t >> 6;
  if ((t & 63) < 32) part[w][e] = pq;
  __syncthreads();

  if ((w & 1) == 0 && (t & 63) < 32) {
    float lg = part[w][e] + part[w+1][e];
    float mx = lg;
    #pragma unroll
    for (int o = 1; o < 32; o <<= 1) mx = fmaxf(mx, __shfl_xor(mx, o, 64));
    float ex = expf(lg - mx);
    float sm = ex;
    #pragma unroll
    for (int o = 1; o < 32; o <<= 1) sm += __shfl_xor(sm, o, 64);
    float prob = ex / sm;

    float pv = prob; int pi = e;
    int myRow = row0 + (w >> 1);
    for (int k = 0; k < 4; ++k) {
      float bv = pv; int bi = pi;
      #pragma unroll
      for (int o = 1; o < 32; o <<= 1) {
        float ov = __shfl_xor(bv, o, 64); int oi = __shfl_xor(bi, o, 64);
        if (ov > bv || (ov == bv && oi < bi)) { bv = ov; bi = oi; }
      }
      if (e == 0) {
        topIdx[myRow*4 + k] = bi; topW[myRow*4 + k] = bv;
        atomicAdd(&hist[bi], 1);
      }
      if (pi == bi) pv = -1.f;
    }
  }
  __syncthreads();
  if (t < 32 && hist[t] > 0) atomicAdd(&counts[t], hist[t]);
}

// ---------------- scan + scatter fused (one block) ----------------
__global__ __launch_bounds__(256) void scan_scatter_kernel(
    const int* __restrict__ counts, int* __restrict__ offsets,
    const int* __restrict__ topIdx, const float* __restrict__ topW,
    int* __restrict__ rows, float* __restrict__ wtp, int* __restrict__ pslot) {
  __shared__ int cur[32];
  int t = threadIdx.x;
  if (t == 0) {
    int acc = 0;
    for (int e = 0; e < 32; ++e) { offsets[e] = acc; cur[e] = acc; acc += counts[e]; }
    offsets[32] = acc;
  }
  __syncthreads();
  for (int i = t; i < 8192; i += 256) {
    int e = topIdx[i];
    int slot = atomicAdd(&cur[e], 1);
    rows[slot] = i >> 2;
    wtp[slot] = topW[i];
    pslot[i] = slot;
  }
}

// ---------------- final: out = x1 + shared(fp16) + sum_k pairOut(fp16)[slot_k] ----------------
__global__ __launch_bounds__(256) void final_kernel(const float* __restrict__ x1, const u16* __restrict__ shOut,
                                                    const u16* __restrict__ pairOut, const int* __restrict__ pslot,
                                                    float* __restrict__ out) {
  int n = blockIdx.x;
  int t = threadIdx.x;
  int s0 = pslot[n*4], s1 = pslot[n*4+1], s2 = pslot[n*4+2], s3 = pslot[n*4+3];
  float4 a  = ((const float4*)(x1 + (size_t)n*1024))[t];
  ushort4 sh = ((const ushort4*)(shOut + (size_t)n*1024))[t];
  ushort4 p0 = ((const ushort4*)(pairOut + (size_t)s0*1024))[t];
  ushort4 p1 = ((const ushort4*)(pairOut + (size_t)s1*1024))[t];
  ushort4 p2 = ((const ushort4*)(pairOut + (size_t)s2*1024))[t];
  ushort4 p3 = ((const ushort4*)(pairOut + (size_t)s3*1024))[t];
  float4 o;
  o.x = a.x + h2f(sh.x) + h2f(p0.x) + h2f(p1.x) + h2f(p2.x) + h2f(p3.x);
  o.y = a.y + h2f(sh.y) + h2f(p0.y) + h2f(p1.y) + h2f(p2.y) + h2f(p3.y);
  o.z = a.z + h2f(sh.z) + h2f(p0.z) + h2f(p1.z) + h2f(p2.z) + h2f(p3.z);
  o.w = a.w + h2f(sh.w) + h2f(p0.w) + h2f(p1.w) + h2f(p2.w) + h2f(p3.w);
  ((float4*)(out + (size_t)n*1024))[t] = o;
}

// ---------------- host ----------------
extern "C" void kernel_launch(void* const* d_in, const int* in_sizes, int n_in,
                              void* d_out, int out_size, void* d_ws, size_t ws_size,
                              hipStream_t stream) {
  const float* x   = (const float*)d_in[0];
  const float* fc  = (const float*)d_in[1];
  const float* fs  = (const float*)d_in[2];
  const float* n1w = (const float*)d_in[3];
  const float* n2w = (const float*)d_in[4];
  const float* wq  = (const float*)d_in[5];
  const float* wk  = (const float*)d_in[6];
  const float* wv  = (const float*)d_in[7];
  const float* wo  = (const float*)d_in[8];
  const float* rw  = (const float*)d_in[9];
  const float* wg  = (const float*)d_in[10];
  const float* wu  = (const float*)d_in[11];
  const float* wd  = (const float*)d_in[12];
  const float* shg = (const float*)d_in[13];
  const float* shu = (const float*)d_in[14];
  const float* shd = (const float*)d_in[15];
  float* out = (float*)d_out;
  (void)in_sizes; (void)n_in; (void)out_size;

  char* p = (char*)d_ws;
  auto alloc = [&](size_t n) { char* r = p; p += (n + 255) & ~(size_t)255; return r; };

  u16* wqkvT  = (u16*)alloc((size_t)1536*1024*2);
  u16* woT    = (u16*)alloc((size_t)1024*1024*2);
  u16* shguT  = (u16*)alloc((size_t)1024*1024*2);   // INTERLEAVED [g0,u0,g1,u1,...][1024]
  u16* shdT   = (u16*)alloc((size_t)1024*512*2);
  u16* wguT   = (u16*)alloc((size_t)32*512*1024*2); // per-expert INTERLEAVED (g,u) rows
  u16* wdT    = (u16*)alloc((size_t)32*1024*256*2);
  u16* hH     = (u16*)alloc((size_t)2048*1024*2);
  float* x1   = (float*)alloc((size_t)2048*1024*4);
  float* h2f_ = (float*)alloc((size_t)2048*1024*4);
  u16* h2b    = (u16*)alloc((size_t)2048*1024*2);
  u16* actb   = (u16*)alloc((size_t)8192*256*2);
  u16* sactb  = (u16*)alloc((size_t)2048*512*2);
  u16* shOut  = (u16*)alloc((size_t)2048*1024*2);   // shared-down out (fp16)
  int* topIdx = (int*)alloc(2048*4*4);
  float* topW = (float*)alloc(2048*4*4);
  int* counts = (int*)alloc(32*4);
  int* offsets = (int*)alloc(33*4);
  int* rows   = (int*)alloc(8192*4);
  float* wtp  = (float*)alloc(8192*4);
  int* pslot  = (int*)alloc(8192*4);
  // alias region: attention temporaries, later reused as pairOut (fp16, 16MB)
  char* regionStart = p;
  u16* qbh = (u16*)alloc((size_t)2048*1024*2);
  u16* kbh = (u16*)alloc((size_t)524288*2);
  u16* vth = (u16*)alloc((size_t)524288*2);
  u16* attnH = (u16*)alloc((size_t)2048*1024*2);
  u16* pairOut = (u16*)regionStart;
  // pairOut (8192*1024*2 = 16MB) must fit inside/after the region
  {
    size_t regionBytes = (size_t)8192*1024*2;
    if ((size_t)(p - regionStart) < regionBytes) p = regionStart + regionBytes;
  }

  size_t needed = (size_t)(p - (char*)d_ws);
  if (needed > ws_size) return;  // insufficient workspace; fail clean

  dim3 blk(256);
  // prep1: ONLY the QKV-gating work (wq/wk/wv transposes + rmsnorm1 + zero_counts)
  prep1_kernel<<<2433, blk, 0, stream>>>(wq, wk, wv, wqkvT, x, n1w, hH, counts);
  // fused QKV projection + RoPE(Q,K) + V-transpose
  gemm_kernel<<<dim3(24, 32), blk, 0, stream>>>(hH, wqkvT, nullptr, nullptr, nullptr, nullptr,
      qbh, kbh, vth, fc, fs,
      nullptr, nullptr, nullptr, nullptr, 2048, 1536, 1024, 0);
  // attention (blocks 0..511) + ALL deferred weight transposes (512..7295)
  attn_prep2_kernel<<<7296, blk, 0, stream>>>(qbh, kbh, vth, attnH,
      wo, shg, shu, shd, wg, wu, wd,
      woT, shguT, shdT, wguT, wdT);
  // output projection + residual (f32 out: residual stream fidelity)
  gemm_kernel<<<dim3(16, 32), blk, 0, stream>>>(attnH, woT, x1, nullptr, nullptr, nullptr,
      nullptr, nullptr, nullptr, nullptr, nullptr,
      x, nullptr, nullptr, nullptr, 2048, 1024, 1024, 0);
  // norm2 -> fp32 (router) + fp16 (experts)
  rmsnorm_kernel<<<2048, blk, 0, stream>>>(x1, n2w, h2b, h2f_);
  // router + grouping
  router_kernel<<<1024, blk, 0, stream>>>(h2f_, rw, topIdx, topW, counts);
  scan_scatter_kernel<<<1, blk, 0, stream>>>(counts, offsets, topIdx, topW, rows, wtp, pslot);
  // shared MLP: fused gate+up GEMM with SILU epilogue -> sactb, then down
  gemm_kernel<<<dim3(16, 32), blk, 0, stream>>>(h2b, shguT, nullptr, nullptr, sactb, nullptr,
      nullptr, nullptr, nullptr, nullptr, nullptr,
      nullptr, nullptr, nullptr, nullptr, 2048, 1024, 1024, 0);
  gemm_kernel<<<dim3(16, 32), blk, 0, stream>>>(sactb, shdT, nullptr, shOut, nullptr, nullptr,
      nullptr, nullptr, nullptr, nullptr, nullptr,
      nullptr, nullptr, nullptr, nullptr, 2048, 1024, 512, 0);
  // MoE experts: grouped gate+up GEMM with SILU(+wtp) epilogue -> actb, then down
  gemm_kernel<<<dim3(8, 32, 32), blk, 0, stream>>>(h2b, wguT, nullptr, nullptr, actb, wtp,
      nullptr, nullptr, nullptr, nullptr, nullptr,
      nullptr, rows, counts, offsets, 0, 512, 1024, 512*1024);
  gemm_kernel<<<dim3(16, 32, 32), blk, 0, stream>>>(actb, wdT, nullptr, pairOut, nullptr, nullptr,
      nullptr, nullptr, nullptr, nullptr, nullptr,
      nullptr, nullptr, counts, offsets, 0, 1024, 256, 1024*256);
  // final residual + combine
  final_kernel<<<2048, blk, 0, stream>>>(x1, shOut, pairOut, pslot, out);
}